// Round 1
// baseline (4534.652 us; speedup 1.0000x reference)
//
#include <hip/hip_runtime.h>
#include <math.h>

// GatedKalmaNet: B=1, L=1024, D=2048, HQ=16, HK=8, HD=128, CONV=4, CHUNK=64,
// Nc=16, NUM_ITER=30, RIDGE=0.02, EPS=1e-6. All f32.

#define LSEQ 1024
#define DM   2048
#define NHQ  16
#define NHK  8
#define HDIM 128
#define NCH  16   // num chunks
#define CSZ  64   // chunk size

// ---------------------------------------------------------------------------
// Generic f32 GEMM: C[M,N] = A[M,K] @ B[K,N].  Tile 128x64, 256 thr, 8x4/thr.
// ---------------------------------------------------------------------------
__global__ __launch_bounds__(256) void gemm_f32(
    const float* __restrict__ A, const float* __restrict__ B,
    float* __restrict__ C, int M, int N, int K) {
  __shared__ float As[16][132];
  __shared__ float Bs[16][68];
  int tid = threadIdx.x;
  int tx = tid & 15, ty = tid >> 4;
  int row0 = blockIdx.y * 128;
  int col0 = blockIdx.x * 64;
  float acc[8][4];
#pragma unroll
  for (int i = 0; i < 8; i++)
#pragma unroll
    for (int j = 0; j < 4; j++) acc[i][j] = 0.f;

  for (int k0 = 0; k0 < K; k0 += 16) {
#pragma unroll
    for (int s = 0; s < 8; ++s) {          // A tile: 128x16
      int l = tid + s * 256;
      int m = l >> 4, kk = l & 15;
      int gm = row0 + m;
      float v = (gm < M) ? A[(size_t)gm * K + k0 + kk] : 0.f;
      As[kk][m] = v;
    }
#pragma unroll
    for (int s = 0; s < 4; ++s) {          // B tile: 16x64
      int l = tid + s * 256;
      int n = l & 63, kk = l >> 6;
      int gn = col0 + n;
      float v = (gn < N) ? B[(size_t)(k0 + kk) * N + gn] : 0.f;
      Bs[kk][n] = v;
    }
    __syncthreads();
#pragma unroll
    for (int kk = 0; kk < 16; ++kk) {
      float a[8], b[4];
#pragma unroll
      for (int i = 0; i < 8; i++) a[i] = As[kk][ty * 8 + i];
#pragma unroll
      for (int j = 0; j < 4; j++) b[j] = Bs[kk][tx * 4 + j];
#pragma unroll
      for (int i = 0; i < 8; i++)
#pragma unroll
        for (int j = 0; j < 4; j++)
          acc[i][j] = fmaf(a[i], b[j], acc[i][j]);
    }
    __syncthreads();
  }
#pragma unroll
  for (int i = 0; i < 8; i++) {
    int gm = row0 + ty * 8 + i;
    if (gm >= M) continue;
#pragma unroll
    for (int j = 0; j < 4; j++) {
      int gn = col0 + tx * 4 + j;
      if (gn < N) C[(size_t)gm * N + gn] = acc[i][j];
    }
  }
}

// ---------------------------------------------------------------------------
// Causal depthwise conv (K=4) + silu (+ scale).  x:[L,nch], w:[nch,4].
// ---------------------------------------------------------------------------
__global__ __launch_bounds__(256) void conv_silu(
    const float* __restrict__ xin, const float* __restrict__ w,
    float* __restrict__ outp, int nch, float scale) {
  int idx = blockIdx.x * 256 + threadIdx.x;   // t*nch + ch, exact cover
  int t = idx / nch, ch = idx - t * nch;
  float acc = 0.f;
#pragma unroll
  for (int j = 0; j < 4; ++j) {
    int tt = t + j - 3;
    float xv = (tt >= 0) ? xin[(size_t)tt * nch + ch] : 0.f;
    acc = fmaf(xv, w[ch * 4 + j], acc);
  }
  float sv = acc / (1.f + expf(-acc));
  outp[idx] = sv * scale;
}

// ---------------------------------------------------------------------------
// Gates: glog = -exp(A_log)*softplus(xa+dt_bias); beta/alpha = sigmoid(.+b).
// ---------------------------------------------------------------------------
__global__ __launch_bounds__(256) void gates_kernel(
    const float* __restrict__ xa, const float* __restrict__ xb,
    const float* __restrict__ xal, const float* __restrict__ A_log,
    const float* __restrict__ dt_bias, const float* __restrict__ bbv,
    const float* __restrict__ balv, float* __restrict__ glog,
    float* __restrict__ beta, float* __restrict__ alpha) {
  int idx = blockIdx.x * 256 + threadIdx.x;   // t*16 + h
  int h = idx & 15;
  float za = xa[idx] + dt_bias[h];
  float sp = fmaxf(za, 0.f) + log1pf(expf(-fabsf(za)));   // stable softplus
  glog[idx] = -expf(A_log[h]) * sp;
  float zb = xb[idx] + bbv[h];
  beta[idx] = 1.f / (1.f + expf(-zb));
  float zc = xal[idx] + balv[h];
  alpha[idx] = 1.f / (1.f + expf(-zc));
}

// ---------------------------------------------------------------------------
// Per-(h,n) inclusive cumsum of glog within chunk + w_end = exp(G-cs)*beta.
// One block of 256 threads; thread = h*16+n.
// ---------------------------------------------------------------------------
__global__ __launch_bounds__(256) void cumsum_kernel(
    const float* __restrict__ glog, const float* __restrict__ beta,
    float* __restrict__ cs, float* __restrict__ wend) {
  int idx = threadIdx.x;            // h*16+n
  int n = idx & 15;
  float acc = 0.f;
  for (int c = 0; c < CSZ; ++c) {
    acc += glog[(n * CSZ + c) * NHQ + (idx >> 4)];
    cs[idx * CSZ + c] = acc;
  }
  float G = acc;
  for (int c = 0; c < CSZ; ++c) {
    wend[idx * CSZ + c] =
        expf(G - cs[idx * CSZ + c]) * beta[(n * CSZ + c) * NHQ + (idx >> 4)];
  }
}

// ---------------------------------------------------------------------------
// Gram increments per (h,n):
//   dH[d,e] = sum_c wend[c]*k[c,d]*k[c,e]   (bit-exactly symmetric)
//   dB[d,e] = sum_c wend[c]*k[c,d]*v[c,e]
// ---------------------------------------------------------------------------
__global__ __launch_bounds__(256) void dhb_kernel(
    const float* __restrict__ ks, const float* __restrict__ vs,
    const float* __restrict__ wend, float* __restrict__ dH,
    float* __restrict__ dB) {
  int bid = blockIdx.x;             // h*16+n
  int h = bid >> 4, n = bid & 15;
  int hk = h >> 1;                  // GQA: expanded head h -> source head h/2
  __shared__ float kt[CSZ][HDIM];   // 32 KB
  __shared__ float vt[CSZ][HDIM];   // 32 KB
  int tid = threadIdx.x;
  for (int l = tid; l < CSZ * HDIM; l += 256) {
    int c = l >> 7, d = l & 127;
    size_t g = (size_t)(n * CSZ + c) * (NHK * HDIM) + hk * HDIM + d;
    kt[c][d] = ks[g];
    vt[c][d] = vs[g];
  }
  __syncthreads();
  int r = tid >> 1;
  int e0 = (tid & 1) << 6;
  float accH[64], accB[64];
#pragma unroll
  for (int j = 0; j < 64; j++) { accH[j] = 0.f; accB[j] = 0.f; }
  for (int c = 0; c < CSZ; ++c) {
    float w = wend[bid * CSZ + c];
    float kr = kt[c][r];
    float a = w * kr;
    const float4* kr4 = (const float4*)(&kt[c][e0]);
    const float4* vr4 = (const float4*)(&vt[c][e0]);
#pragma unroll
    for (int j4 = 0; j4 < 16; ++j4) {
      float4 kv = kr4[j4];
      float4 vv = vr4[j4];
      // symmetric product form: fma(w, k[r]*k[e], .) == fma(w, k[e]*k[r], .)
      accH[j4*4+0] = fmaf(w, kr * kv.x, accH[j4*4+0]);
      accH[j4*4+1] = fmaf(w, kr * kv.y, accH[j4*4+1]);
      accH[j4*4+2] = fmaf(w, kr * kv.z, accH[j4*4+2]);
      accH[j4*4+3] = fmaf(w, kr * kv.w, accH[j4*4+3]);
      accB[j4*4+0] = fmaf(a, vv.x, accB[j4*4+0]);
      accB[j4*4+1] = fmaf(a, vv.y, accB[j4*4+1]);
      accB[j4*4+2] = fmaf(a, vv.z, accB[j4*4+2]);
      accB[j4*4+3] = fmaf(a, vv.w, accB[j4*4+3]);
    }
  }
  size_t base = ((size_t)bid * HDIM + r) * HDIM + e0;
#pragma unroll
  for (int j = 0; j < 64; j++) { dH[base + j] = accH[j]; dB[base + j] = accB[j]; }
}

// ---------------------------------------------------------------------------
// Inter-chunk scan (in-place): dH/dB[n] overwritten with state at chunk start.
// A = H0 + ridge on diagonal is stored directly (only consumer is the solver).
// thread = (h, de) elementwise, serial over n.
// ---------------------------------------------------------------------------
__global__ __launch_bounds__(256) void scan_kernel(
    float* __restrict__ dH, float* __restrict__ dB,
    const float* __restrict__ cs) {
  int idx = blockIdx.x * 256 + threadIdx.x;  // h*16384 + de
  int h = idx >> 14, de = idx & 16383;
  float Hs = 0.f, Bs = 0.f;
  bool diag = ((de % 129) == 0);             // de = d*128+e, d==e
#pragma unroll 1
  for (int n = 0; n < NCH; ++n) {
    size_t off = ((size_t)(h * 16 + n) << 14) + de;
    float dh = dH[off], db = dB[off];
    dH[off] = diag ? (Hs + 0.02f) : Hs;      // A = H0 + RIDGE*I
    dB[off] = Bs;                            // B0
    float g = expf(cs[(h * 16 + n) * CSZ + (CSZ - 1)]);
    Hs = fmaf(g, Hs, dh);
    Bs = fmaf(g, Bs, db);
  }
}

// ---------------------------------------------------------------------------
// Chebyshev semi-iteration solve A X = B0 per (h,n).  One block per (h,n).
// A (with ridge) in global (read via exact symmetry A[i][e]==A[e][i]);
// dvec in LDS (64 KB); x, r in registers (8x8 tile per thread).
// X written in-place over B0.
// ---------------------------------------------------------------------------
__global__ __launch_bounds__(256) void cheb_kernel(
    const float* __restrict__ Aall, float* __restrict__ Ball) {
  int bid = blockIdx.x;                       // h*16+n
  size_t gbase = (size_t)bid << 14;
  const float* __restrict__ Ag = Aall + gbase;
  float* __restrict__ Bg = Ball + gbase;
  __shared__ float dv[128 * 128];             // 64 KB exactly
  int tid = threadIdx.x;
  int lane = tid & 63;

  // lmax = trace(A) (per-wave redundant shuffle reduction, no LDS)
  float tv = Ag[lane * 129] + Ag[(lane + 64) * 129];
#pragma unroll
  for (int off = 32; off; off >>= 1) tv += __shfl_down(tv, off);
  float lmax = __shfl(tv, 0);

  const float lmin = 0.02f;
  float theta = 0.5f * (lmax + lmin);
  float delta = 0.5f * (lmax - lmin);
  float sigma1 = theta / delta;
  float rho = delta / theta;                  // 1/sigma1
  float invtheta = 1.f / theta;

  int ti = tid >> 4, tj = tid & 15;
  int i0 = ti * 8, j0 = tj * 8;
  float x[8][8], rr[8][8];
#pragma unroll
  for (int ii = 0; ii < 8; ii++) {
    float4 b0 = *(const float4*)(Bg + (i0 + ii) * 128 + j0);
    float4 b1 = *(const float4*)(Bg + (i0 + ii) * 128 + j0 + 4);
    float t0[8] = {b0.x, b0.y, b0.z, b0.w, b1.x, b1.y, b1.z, b1.w};
#pragma unroll
    for (int jj = 0; jj < 8; jj++) {
      rr[ii][jj] = t0[jj];
      x[ii][jj] = 0.f;
      dv[(i0 + ii) * 128 + j0 + jj] = t0[jj] * invtheta;
    }
  }
  __syncthreads();

  for (int it = 0; it < 30; ++it) {
#pragma unroll 2
    for (int e = 0; e < 128; ++e) {
      // A[i][e] fetched as A[e][i] (exact symmetry), coalesced within wave
      float4 a0 = *(const float4*)(Ag + e * 128 + i0);
      float4 a1 = *(const float4*)(Ag + e * 128 + i0 + 4);
      float4 c0 = *(const float4*)(dv + e * 128 + j0);
      float4 c1 = *(const float4*)(dv + e * 128 + j0 + 4);
      float a[8] = {a0.x, a0.y, a0.z, a0.w, a1.x, a1.y, a1.z, a1.w};
      float b[8] = {c0.x, c0.y, c0.z, c0.w, c1.x, c1.y, c1.z, c1.w};
#pragma unroll
      for (int ii = 0; ii < 8; ii++)
#pragma unroll
        for (int jj = 0; jj < 8; jj++)
          rr[ii][jj] = fmaf(-a[ii], b[jj], rr[ii][jj]);
    }
    float rho_n = 1.f / (2.f * sigma1 - rho);
    float c1s = rho_n * rho;
    float c2s = 2.f * rho_n / delta;
    __syncthreads();                 // all matmul reads of dv complete
#pragma unroll
    for (int ii = 0; ii < 8; ii++)
#pragma unroll
      for (int jj = 0; jj < 8; jj++) {
        int off = (i0 + ii) * 128 + j0 + jj;
        float dold = dv[off];
        x[ii][jj] += dold;           // x += dvec_old
        dv[off] = fmaf(c1s, dold, c2s * rr[ii][jj]);
      }
    rho = rho_n;
    __syncthreads();
  }
#pragma unroll
  for (int ii = 0; ii < 8; ii++)
#pragma unroll
    for (int jj = 0; jj < 8; jj++)
      Bg[(i0 + ii) * 128 + j0 + jj] = x[ii][jj];   // X over B0 (in-place safe)
}

// ---------------------------------------------------------------------------
// Attention per (h,n): o = exp(cs)*(q@X) + tril-gated (q@k^T)@v + alpha*v.
// qb holds q then (reused) scores; wb holds X-tiles, then k, then v.
// ---------------------------------------------------------------------------
__global__ __launch_bounds__(256) void attn_kernel(
    const float* __restrict__ qs, const float* __restrict__ ks,
    const float* __restrict__ vs, const float* __restrict__ X,
    const float* __restrict__ cs, const float* __restrict__ beta,
    const float* __restrict__ alpha, float* __restrict__ o) {
  int bid = blockIdx.x;             // h*16+n
  int h = bid >> 4, n = bid & 15;
  int hk = h >> 1;
  __shared__ float qb[CSZ * HDIM];  // 32 KB (later: scores, pitch 65)
  __shared__ float wb[CSZ * HDIM];  // 32 KB (X tiles / k / v)
  int tid = threadIdx.x;

  for (int l = tid; l < CSZ * HDIM; l += 256) {
    int c = l >> 7, d = l & 127;
    qb[l] = qs[(size_t)(n * CSZ + c) * (NHQ * HDIM) + h * HDIM + d];
  }
  __syncthreads();

  int c = tid >> 2;
  int e0 = (tid & 3) << 5;
  float acc[32];
#pragma unroll
  for (int j = 0; j < 32; j++) acc[j] = 0.f;

  // ---- phase 1: o_inter = q @ X (X staged in 16-row tiles) ----
  size_t xbase = (size_t)bid << 14;
  for (int d0 = 0; d0 < 128; d0 += 16) {
    __syncthreads();
    for (int l = tid; l < 16 * 128; l += 256)
      wb[l] = X[xbase + d0 * 128 + l];
    __syncthreads();
#pragma unroll
    for (int dd = 0; dd < 16; ++dd) {
      float a = qb[c * 128 + d0 + dd];
      const float4* xr = (const float4*)(wb + dd * 128 + e0);
#pragma unroll
      for (int j4 = 0; j4 < 8; ++j4) {
        float4 xv = xr[j4];
        acc[j4*4+0] = fmaf(a, xv.x, acc[j4*4+0]);
        acc[j4*4+1] = fmaf(a, xv.y, acc[j4*4+1]);
        acc[j4*4+2] = fmaf(a, xv.z, acc[j4*4+2]);
        acc[j4*4+3] = fmaf(a, xv.w, acc[j4*4+3]);
      }
    }
  }
  float csc = cs[bid * CSZ + c];
  float esc = expf(csc);
#pragma unroll
  for (int j = 0; j < 32; j++) acc[j] *= esc;

  // ---- phase 2: scores s[c,j] = (q.k) * exp(cs_c - cs_j) * beta_j, j<=c ----
  __syncthreads();
  for (int l = tid; l < CSZ * HDIM; l += 256) {
    int cc = l >> 7, d = l & 127;
    wb[l] = ks[(size_t)(n * CSZ + cc) * (NHK * HDIM) + hk * HDIM + d];
  }
  __syncthreads();
  int jj0 = (tid & 3) << 4;
  float sreg[16];
#pragma unroll
  for (int j = 0; j < 16; ++j) {
    int jc = jj0 + j;
    float dotv = 0.f;
    if (jc <= c) {
      const float4* qr = (const float4*)(qb + c * 128);
      const float4* kr = (const float4*)(wb + jc * 128);
#pragma unroll
      for (int d4 = 0; d4 < 32; ++d4) {
        float4 qv = qr[d4];
        float4 kv = kr[d4];
        dotv = fmaf(qv.x, kv.x, dotv);
        dotv = fmaf(qv.y, kv.y, dotv);
        dotv = fmaf(qv.z, kv.z, dotv);
        dotv = fmaf(qv.w, kv.w, dotv);
      }
      float csj = cs[bid * CSZ + jc];
      float bj = beta[(n * CSZ + jc) * NHQ + h];
      dotv *= expf(csc - csj) * bj;
    }
    sreg[j] = dotv;
  }
  __syncthreads();                  // all reads of q (qb) and k (wb) done
#pragma unroll
  for (int j = 0; j < 16; ++j) qb[c * 65 + jj0 + j] = sreg[j];  // s, pitch 65
  for (int l = tid; l < CSZ * HDIM; l += 256) {                 // v into wb
    int cc = l >> 7, d = l & 127;
    wb[l] = vs[(size_t)(n * CSZ + cc) * (NHK * HDIM) + hk * HDIM + d];
  }
  __syncthreads();

  // ---- phase 3: o += s @ v, then + alpha*v ----
#pragma unroll 4
  for (int jc = 0; jc < CSZ; ++jc) {
    float sv = qb[c * 65 + jc];
    const float4* vr = (const float4*)(wb + jc * 128 + e0);
#pragma unroll
    for (int j4 = 0; j4 < 8; ++j4) {
      float4 vv = vr[j4];
      acc[j4*4+0] = fmaf(sv, vv.x, acc[j4*4+0]);
      acc[j4*4+1] = fmaf(sv, vv.y, acc[j4*4+1]);
      acc[j4*4+2] = fmaf(sv, vv.z, acc[j4*4+2]);
      acc[j4*4+3] = fmaf(sv, vv.w, acc[j4*4+3]);
    }
  }
  float al = alpha[(n * CSZ + c) * NHQ + h];
  {
    const float4* vr = (const float4*)(wb + c * 128 + e0);
#pragma unroll
    for (int j4 = 0; j4 < 8; ++j4) {
      float4 vv = vr[j4];
      acc[j4*4+0] = fmaf(al, vv.x, acc[j4*4+0]);
      acc[j4*4+1] = fmaf(al, vv.y, acc[j4*4+1]);
      acc[j4*4+2] = fmaf(al, vv.z, acc[j4*4+2]);
      acc[j4*4+3] = fmaf(al, vv.w, acc[j4*4+3]);
    }
  }
  size_t ob = ((size_t)(n * CSZ + c) * NHQ + h) * HDIM + e0;
#pragma unroll
  for (int j4 = 0; j4 < 8; ++j4) {
    float4 st = make_float4(acc[j4*4+0], acc[j4*4+1], acc[j4*4+2], acc[j4*4+3]);
    *(float4*)(o + ob + j4 * 4) = st;
  }
}

// ---------------------------------------------------------------------------
// Gated RMSNorm: onorm = o * rsqrt(mean(o^2)+eps) * norm_w * silu(g).
// One wave per row (row = t*16+h, 128 elems).
// ---------------------------------------------------------------------------
__global__ __launch_bounds__(256) void rmsnorm_kernel(
    const float* __restrict__ o, const float* __restrict__ xg,
    const float* __restrict__ norm_w, float* __restrict__ onorm) {
  int wave = threadIdx.x >> 6, lane = threadIdx.x & 63;
  int row = blockIdx.x * 4 + wave;
  size_t base = (size_t)row * HDIM;
  float v0 = o[base + lane], v1 = o[base + lane + 64];
  float ss = fmaf(v0, v0, v1 * v1);
#pragma unroll
  for (int off = 32; off; off >>= 1) ss += __shfl_down(ss, off);
  ss = __shfl(ss, 0);
  float rinv = rsqrtf(ss * (1.f / 128.f) + 1e-6f);
  float g0 = xg[base + lane], g1 = xg[base + lane + 64];
  float s0 = g0 / (1.f + expf(-g0));
  float s1 = g1 / (1.f + expf(-g1));
  onorm[base + lane]      = v0 * rinv * norm_w[lane] * s0;
  onorm[base + lane + 64] = v1 * rinv * norm_w[lane + 64] * s1;
}

// ---------------------------------------------------------------------------
extern "C" void kernel_launch(void* const* d_in, const int* in_sizes, int n_in,
                              void* d_out, int out_size, void* d_ws,
                              size_t ws_size, hipStream_t stream) {
  (void)in_sizes; (void)n_in; (void)out_size; (void)ws_size;
  const float* x      = (const float*)d_in[0];
  const float* Wq     = (const float*)d_in[1];
  const float* Wk     = (const float*)d_in[2];
  const float* Wv     = (const float*)d_in[3];
  const float* convq  = (const float*)d_in[4];
  const float* convk  = (const float*)d_in[5];
  const float* convv  = (const float*)d_in[6];
  const float* Wa     = (const float*)d_in[7];
  const float* A_log  = (const float*)d_in[8];
  const float* dtb    = (const float*)d_in[9];
  const float* Wb     = (const float*)d_in[10];
  const float* bbv    = (const float*)d_in[11];
  const float* Wal    = (const float*)d_in[12];
  const float* balv   = (const float*)d_in[13];
  const float* Wg     = (const float*)d_in[14];
  const float* norm_w = (const float*)d_in[15];
  const float* Wo     = (const float*)d_in[16];
  float* out = (float*)d_out;

  // workspace layout (floats); total ~23.2M floats = ~93 MB
  float* p = (float*)d_ws;
  float* xq    = p; p += 2097152;   // [L,2048]
  float* xk    = p; p += 1048576;   // [L,1024]
  float* xv    = p; p += 1048576;
  float* xg    = p; p += 2097152;
  float* xa    = p; p += 16384;     // [L,16]
  float* xb    = p; p += 16384;
  float* xal   = p; p += 16384;
  float* qs    = p; p += 2097152;   // post-conv q (scaled)
  float* ks2   = p; p += 1048576;
  float* vs2   = p; p += 1048576;
  float* glog  = p; p += 16384;
  float* beta  = p; p += 16384;
  float* alpha = p; p += 16384;
  float* csb   = p; p += 16384;     // [h*16+n][64]
  float* wend  = p; p += 16384;
  float* dHn   = p; p += 4194304;   // -> A (=H0+ridge) after scan
  float* dBn   = p; p += 4194304;   // -> B0 after scan -> X after cheb
  float* ob    = p; p += 2097152;   // o pre-norm [t*16+h][128]
  float* onorm = p; p += 2097152;

  dim3 blk(256);
  // projections
  gemm_f32<<<dim3(32, 8), blk, 0, stream>>>(x, Wq, xq, 1024, 2048, 2048);
  gemm_f32<<<dim3(16, 8), blk, 0, stream>>>(x, Wk, xk, 1024, 1024, 2048);
  gemm_f32<<<dim3(16, 8), blk, 0, stream>>>(x, Wv, xv, 1024, 1024, 2048);
  gemm_f32<<<dim3(32, 8), blk, 0, stream>>>(x, Wg, xg, 1024, 2048, 2048);
  gemm_f32<<<dim3(1, 8), blk, 0, stream>>>(x, Wa, xa, 1024, 16, 2048);
  gemm_f32<<<dim3(1, 8), blk, 0, stream>>>(x, Wb, xb, 1024, 16, 2048);
  gemm_f32<<<dim3(1, 8), blk, 0, stream>>>(x, Wal, xal, 1024, 16, 2048);
  // causal conv + silu (q scaled by HD^-0.5)
  conv_silu<<<8192, blk, 0, stream>>>(xq, convq, qs, 2048, 0.08838834764831845f);
  conv_silu<<<4096, blk, 0, stream>>>(xk, convk, ks2, 1024, 1.0f);
  conv_silu<<<4096, blk, 0, stream>>>(xv, convv, vs2, 1024, 1.0f);
  // gates + per-chunk cumulative decay
  gates_kernel<<<64, blk, 0, stream>>>(xa, xb, xal, A_log, dtb, bbv, balv,
                                       glog, beta, alpha);
  cumsum_kernel<<<1, blk, 0, stream>>>(glog, beta, csb, wend);
  // gram increments, inter-chunk scan, Chebyshev solve
  dhb_kernel<<<256, blk, 0, stream>>>(ks2, vs2, wend, dHn, dBn);
  scan_kernel<<<1024, blk, 0, stream>>>(dHn, dBn, csb);
  cheb_kernel<<<256, blk, 0, stream>>>(dHn, dBn);   // X -> dBn in place
  // attention (inter + intra + alpha*v)
  attn_kernel<<<256, blk, 0, stream>>>(qs, ks2, vs2, dBn, csb, beta, alpha, ob);
  // gated RMSNorm + output projection
  rmsnorm_kernel<<<4096, blk, 0, stream>>>(ob, xg, norm_w, onorm);
  gemm_f32<<<dim3(32, 8), blk, 0, stream>>>(onorm, Wo, out, 1024, 2048, 2048);
}

// Round 3
// 1103.880 us; speedup vs baseline: 4.1079x; 4.1079x over previous
//
#include <hip/hip_runtime.h>
#include <math.h>

// GatedKalmaNet: B=1, L=1024, D=2048, HQ=16, HK=8, HD=128, CONV=4, CHUNK=64,
// Nc=16, NUM_ITER=30, RIDGE=0.02, EPS=1e-6.

#define LSEQ 1024
#define DM   2048
#define NHQ  16
#define NHK  8
#define HDIM 128
#define NCH  16
#define CSZ  64

typedef __attribute__((ext_vector_type(8))) short short8;
typedef __attribute__((ext_vector_type(4))) float floatx4;

// f32 -> bf16, round-to-nearest-even (bit-exact with __float2bfloat16 for
// finite inputs; NaN maps to a NaN pattern).
__device__ __forceinline__ unsigned short f2bf(float f) {
  unsigned int u = __float_as_uint(f);
  u += 0x7fffu + ((u >> 16) & 1u);
  return (unsigned short)(u >> 16);
}

// ---------------------------------------------------------------------------
// Elementwise f32 -> bf16 cast (4 elems/thread).
// ---------------------------------------------------------------------------
__global__ __launch_bounds__(256) void castbf(
    const float* __restrict__ a, unsigned short* __restrict__ o) {
  int i = blockIdx.x * 256 + threadIdx.x;
  float4 v = ((const float4*)a)[i];
  ushort4 u;
  u.x = f2bf(v.x); u.y = f2bf(v.y); u.z = f2bf(v.z); u.w = f2bf(v.w);
  ((ushort4*)o)[i] = u;
}

// ---------------------------------------------------------------------------
// Transpose-cast: W[K][N] f32 -> Wt[N][K] bf16.  32x32 LDS tiles.
// grid = (N/32, K/32)
// ---------------------------------------------------------------------------
__global__ __launch_bounds__(256) void tcast(
    const float* __restrict__ W, unsigned short* __restrict__ Wt,
    int K, int N) {
  __shared__ float t[32][33];
  int bn = blockIdx.x, bk = blockIdx.y;
  int tid = threadIdx.x;
  int r = tid >> 5, c = tid & 31;
#pragma unroll
  for (int i = 0; i < 4; ++i)
    t[r + i * 8][c] = W[(size_t)(bk * 32 + r + i * 8) * N + bn * 32 + c];
  __syncthreads();
#pragma unroll
  for (int i = 0; i < 4; ++i)
    Wt[(size_t)(bn * 32 + r + i * 8) * K + bk * 32 + c] =
        f2bf(t[c][r + i * 8]);
}

// ---------------------------------------------------------------------------
// bf16 MFMA GEMM: C[M,N](f32) = A[M,K](bf16) @ Bt[N,K](bf16)^T.
// BM=128 BN=64 BK=64; 256 thr = 4 waves (2x2); wave tile 64x32 (4x2 of 16x16).
// grid = (N/64, M/128).  M,N,K multiples of tile dims (no bounds checks).
// ---------------------------------------------------------------------------
__global__ __launch_bounds__(256) void gemm_bf16(
    const unsigned short* __restrict__ A, const unsigned short* __restrict__ Bt,
    float* __restrict__ C, int M, int N, int K) {
  __shared__ unsigned short As[128 * 72];
  __shared__ unsigned short Bs[64 * 72];
  int tid = threadIdx.x;
  int wave = tid >> 6, lane = tid & 63;
  int ln = lane & 15, hi = lane >> 4;
  int wm = wave & 1, wn = wave >> 1;
  int m0 = blockIdx.y * 128, n0 = blockIdx.x * 64;

  floatx4 acc[4][2];
#pragma unroll
  for (int mt = 0; mt < 4; ++mt)
#pragma unroll
    for (int nt = 0; nt < 2; ++nt) acc[mt][nt] = (floatx4)(0.f);

  for (int k0 = 0; k0 < K; k0 += 64) {
    // stage A: 128 rows x 64 bf16 (8-bf16 chunks, 4 per thread)
#pragma unroll
    for (int g = 0; g < 4; ++g) {
      int l = tid + g * 256;
      int m = l >> 3, go = l & 7;
      uint4 v = *(const uint4*)(A + (size_t)(m0 + m) * K + k0 + go * 8);
      *(uint4*)(As + m * 72 + go * 8) = v;
    }
#pragma unroll
    for (int g = 0; g < 2; ++g) {
      int l = tid + g * 256;
      int n = l >> 3, go = l & 7;
      uint4 v = *(const uint4*)(Bt + (size_t)(n0 + n) * K + k0 + go * 8);
      *(uint4*)(Bs + n * 72 + go * 8) = v;
    }
    __syncthreads();
#pragma unroll
    for (int kb = 0; kb < 2; ++kb) {
      short8 a[4], b[2];
#pragma unroll
      for (int mt = 0; mt < 4; ++mt)
        a[mt] = *(const short8*)(As + (wm * 64 + mt * 16 + ln) * 72 + kb * 32 + hi * 8);
#pragma unroll
      for (int nt = 0; nt < 2; ++nt)
        b[nt] = *(const short8*)(Bs + (wn * 32 + nt * 16 + ln) * 72 + kb * 32 + hi * 8);
#pragma unroll
      for (int mt = 0; mt < 4; ++mt)
#pragma unroll
        for (int nt = 0; nt < 2; ++nt)
          acc[mt][nt] = __builtin_amdgcn_mfma_f32_16x16x32_bf16(
              a[mt], b[nt], acc[mt][nt], 0, 0, 0);
    }
    __syncthreads();
  }
  // C/D layout (m89-verified): col = lane&15, row = (lane>>4)*4 + reg
#pragma unroll
  for (int mt = 0; mt < 4; ++mt)
#pragma unroll
    for (int nt = 0; nt < 2; ++nt) {
      int col = n0 + wn * 32 + nt * 16 + ln;
      int rowb = m0 + wm * 64 + mt * 16 + hi * 4;
#pragma unroll
      for (int r = 0; r < 4; ++r)
        C[(size_t)(rowb + r) * N + col] = acc[mt][nt][r];
    }
}

// ---------------------------------------------------------------------------
// Causal depthwise conv (K=4) + silu (+ scale).  x:[L,nch], w:[nch,4].
// ---------------------------------------------------------------------------
__global__ __launch_bounds__(256) void conv_silu(
    const float* __restrict__ xin, const float* __restrict__ w,
    float* __restrict__ outp, int nch, float scale) {
  int idx = blockIdx.x * 256 + threadIdx.x;
  int t = idx / nch, ch = idx - t * nch;
  float acc = 0.f;
#pragma unroll
  for (int j = 0; j < 4; ++j) {
    int tt = t + j - 3;
    float xv = (tt >= 0) ? xin[(size_t)tt * nch + ch] : 0.f;
    acc = fmaf(xv, w[ch * 4 + j], acc);
  }
  float sv = acc / (1.f + expf(-acc));
  outp[idx] = sv * scale;
}

// ---------------------------------------------------------------------------
// Fused skinny projections + gate nonlinearities.  One block per timestep.
// y = x[t] @ {Wa,Wb,Walpha} (48 dots of K=2048), then gate math.
// ---------------------------------------------------------------------------
__global__ __launch_bounds__(256) void gates_fused(
    const float* __restrict__ x, const float* __restrict__ Wa,
    const float* __restrict__ Wb, const float* __restrict__ Wal,
    const float* __restrict__ A_log, const float* __restrict__ dtb,
    const float* __restrict__ bbv, const float* __restrict__ balv,
    float* __restrict__ glog, float* __restrict__ beta,
    float* __restrict__ alpha) {
  int t = blockIdx.x;
  __shared__ float xr[2048];
  __shared__ float part[256];
  int tid = threadIdx.x;
  for (int i = tid; i < 512; i += 256)
    ((float4*)xr)[i] = ((const float4*)(x + (size_t)t * 2048))[i];
  __syncthreads();
  int o = tid >> 2, p = tid & 3;
  float s = 0.f;
  if (o < 48) {
    const float* W = (o < 16) ? Wa : (o < 32) ? Wb : Wal;
    int h = o & 15;
    int k0 = p * 512;
    for (int k = k0; k < k0 + 512; ++k) s = fmaf(xr[k], W[k * 16 + h], s);
  }
  part[tid] = s;
  __syncthreads();
  if (o < 48 && p == 0) {
    float dot = part[tid] + part[tid + 1] + part[tid + 2] + part[tid + 3];
    int h = o & 15;
    if (o < 16) {
      float za = dot + dtb[h];
      float sp = fmaxf(za, 0.f) + log1pf(expf(-fabsf(za)));
      glog[t * 16 + h] = -expf(A_log[h]) * sp;
    } else if (o < 32) {
      beta[t * 16 + h] = 1.f / (1.f + expf(-(dot + bbv[h])));
    } else {
      alpha[t * 16 + h] = 1.f / (1.f + expf(-(dot + balv[h])));
    }
  }
}

// ---------------------------------------------------------------------------
// Per-(h,n) inclusive cumsum of glog within chunk + w_end = exp(G-cs)*beta.
// ---------------------------------------------------------------------------
__global__ __launch_bounds__(256) void cumsum_kernel(
    const float* __restrict__ glog, const float* __restrict__ beta,
    float* __restrict__ cs, float* __restrict__ wend) {
  int idx = threadIdx.x;            // h*16+n
  int n = idx & 15;
  float acc = 0.f;
  for (int c = 0; c < CSZ; ++c) {
    acc += glog[(n * CSZ + c) * NHQ + (idx >> 4)];
    cs[idx * CSZ + c] = acc;
  }
  float G = acc;
  for (int c = 0; c < CSZ; ++c) {
    wend[idx * CSZ + c] =
        expf(G - cs[idx * CSZ + c]) * beta[(n * CSZ + c) * NHQ + (idx >> 4)];
  }
}

// ---------------------------------------------------------------------------
// Gram increments per (h,n): dH = sum_c w*k*k^T (exactly symmetric), dB = w*k*v^T
// ---------------------------------------------------------------------------
__global__ __launch_bounds__(256) void dhb_kernel(
    const float* __restrict__ ks, const float* __restrict__ vs,
    const float* __restrict__ wend, float* __restrict__ dH,
    float* __restrict__ dB) {
  int bid = blockIdx.x;             // h*16+n
  int h = bid >> 4, n = bid & 15;
  int hk = h >> 1;
  __shared__ float kt[CSZ][HDIM];
  __shared__ float vt[CSZ][HDIM];
  int tid = threadIdx.x;
  for (int l = tid; l < CSZ * HDIM; l += 256) {
    int c = l >> 7, d = l & 127;
    size_t g = (size_t)(n * CSZ + c) * (NHK * HDIM) + hk * HDIM + d;
    kt[c][d] = ks[g];
    vt[c][d] = vs[g];
  }
  __syncthreads();
  int r = tid >> 1;
  int e0 = (tid & 1) << 6;
  float accH[64], accB[64];
#pragma unroll
  for (int j = 0; j < 64; j++) { accH[j] = 0.f; accB[j] = 0.f; }
  for (int c = 0; c < CSZ; ++c) {
    float w = wend[bid * CSZ + c];
    float kr = kt[c][r];
    float a = w * kr;
    const float4* kr4 = (const float4*)(&kt[c][e0]);
    const float4* vr4 = (const float4*)(&vt[c][e0]);
#pragma unroll
    for (int j4 = 0; j4 < 16; ++j4) {
      float4 kv = kr4[j4];
      float4 vv = vr4[j4];
      accH[j4*4+0] = fmaf(w, kr * kv.x, accH[j4*4+0]);
      accH[j4*4+1] = fmaf(w, kr * kv.y, accH[j4*4+1]);
      accH[j4*4+2] = fmaf(w, kr * kv.z, accH[j4*4+2]);
      accH[j4*4+3] = fmaf(w, kr * kv.w, accH[j4*4+3]);
      accB[j4*4+0] = fmaf(a, vv.x, accB[j4*4+0]);
      accB[j4*4+1] = fmaf(a, vv.y, accB[j4*4+1]);
      accB[j4*4+2] = fmaf(a, vv.z, accB[j4*4+2]);
      accB[j4*4+3] = fmaf(a, vv.w, accB[j4*4+3]);
    }
  }
  size_t base = ((size_t)bid * HDIM + r) * HDIM + e0;
#pragma unroll
  for (int j = 0; j < 64; j++) { dH[base + j] = accH[j]; dB[base + j] = accB[j]; }
}

// ---------------------------------------------------------------------------
// Inter-chunk scan (in-place): store state at chunk start; A gets +ridge diag.
// ---------------------------------------------------------------------------
__global__ __launch_bounds__(256) void scan_kernel(
    float* __restrict__ dH, float* __restrict__ dB,
    const float* __restrict__ cs) {
  int idx = blockIdx.x * 256 + threadIdx.x;  // h*16384 + de
  int h = idx >> 14, de = idx & 16383;
  float Hs = 0.f, Bs = 0.f;
  bool diag = ((de % 129) == 0);
#pragma unroll 1
  for (int n = 0; n < NCH; ++n) {
    size_t off = ((size_t)(h * 16 + n) << 14) + de;
    float dh = dH[off], db = dB[off];
    dH[off] = diag ? (Hs + 0.02f) : Hs;
    dB[off] = Bs;
    float g = expf(cs[(h * 16 + n) * CSZ + (CSZ - 1)]);
    Hs = fmaf(g, Hs, dh);
    Bs = fmaf(g, Bs, db);
  }
}

// ---------------------------------------------------------------------------
// Chebyshev solve A X = B0 per (h,n).  512 thr; dvec in regs + LDS mirror.
// Thread tile: 8 rows (i0=(tid>>5)*8) x 4 cols (c0=(tid&31)*4).
// All LDS traffic is float4 (bank-balanced); A read via exact symmetry.
// ---------------------------------------------------------------------------
__global__ __launch_bounds__(512) void cheb_kernel(
    const float* __restrict__ Aall, float* __restrict__ Ball) {
  int bid = blockIdx.x;
  size_t gbase = (size_t)bid << 14;
  const float* __restrict__ Ag = Aall + gbase;
  float* __restrict__ Bg = Ball + gbase;
  __shared__ float dv[128 * 128];
  int tid = threadIdx.x;
  int lane = tid & 63;
  int i0 = (tid >> 5) * 8;
  int c0 = (tid & 31) * 4;

  // lmax = trace(A), redundant per-wave shuffle reduction
  float tv = Ag[lane * 129] + Ag[(lane + 64) * 129];
#pragma unroll
  for (int off = 32; off; off >>= 1) tv += __shfl_down(tv, off);
  float lmax = __shfl(tv, 0);

  const float lmin = 0.02f;
  float theta = 0.5f * (lmax + lmin);
  float delta = 0.5f * (lmax - lmin);
  float sigma1 = theta / delta;
  float rho = delta / theta;
  float invtheta = 1.f / theta;

  float x[8][4], rr[8][4], dreg[8][4];
#pragma unroll
  for (int ii = 0; ii < 8; ++ii) {
    float4 b = *(const float4*)(Bg + (i0 + ii) * 128 + c0);
    rr[ii][0] = b.x; rr[ii][1] = b.y; rr[ii][2] = b.z; rr[ii][3] = b.w;
    x[ii][0] = x[ii][1] = x[ii][2] = x[ii][3] = 0.f;
    float4 d = make_float4(b.x * invtheta, b.y * invtheta,
                           b.z * invtheta, b.w * invtheta);
    dreg[ii][0] = d.x; dreg[ii][1] = d.y; dreg[ii][2] = d.z; dreg[ii][3] = d.w;
    *(float4*)(dv + (i0 + ii) * 128 + c0) = d;
  }
  __syncthreads();

  for (int it = 0; it < 30; ++it) {
#pragma unroll 4
    for (int e = 0; e < 128; ++e) {
      float4 a0 = *(const float4*)(Ag + e * 128 + i0);      // A[e][i0..] == A[i0..][e]
      float4 a1 = *(const float4*)(Ag + e * 128 + i0 + 4);
      float4 d  = *(const float4*)(dv + e * 128 + c0);
      float av[8] = {a0.x, a0.y, a0.z, a0.w, a1.x, a1.y, a1.z, a1.w};
#pragma unroll
      for (int ii = 0; ii < 8; ++ii) {
        rr[ii][0] = fmaf(-av[ii], d.x, rr[ii][0]);
        rr[ii][1] = fmaf(-av[ii], d.y, rr[ii][1]);
        rr[ii][2] = fmaf(-av[ii], d.z, rr[ii][2]);
        rr[ii][3] = fmaf(-av[ii], d.w, rr[ii][3]);
      }
    }
    float rho_n = 1.f / (2.f * sigma1 - rho);
    float c1s = rho_n * rho;
    float c2s = 2.f * rho_n / delta;
    __syncthreads();                 // matmul reads of dv done
#pragma unroll
    for (int ii = 0; ii < 8; ++ii) {
      float4 dn;
      x[ii][0] += dreg[ii][0]; dn.x = fmaf(c1s, dreg[ii][0], c2s * rr[ii][0]);
      x[ii][1] += dreg[ii][1]; dn.y = fmaf(c1s, dreg[ii][1], c2s * rr[ii][1]);
      x[ii][2] += dreg[ii][2]; dn.z = fmaf(c1s, dreg[ii][2], c2s * rr[ii][2]);
      x[ii][3] += dreg[ii][3]; dn.w = fmaf(c1s, dreg[ii][3], c2s * rr[ii][3]);
      dreg[ii][0] = dn.x; dreg[ii][1] = dn.y; dreg[ii][2] = dn.z; dreg[ii][3] = dn.w;
      *(float4*)(dv + (i0 + ii) * 128 + c0) = dn;
    }
    rho = rho_n;
    __syncthreads();
  }
#pragma unroll
  for (int ii = 0; ii < 8; ++ii) {
    float4 xs = make_float4(x[ii][0], x[ii][1], x[ii][2], x[ii][3]);
    *(float4*)(Bg + (i0 + ii) * 128 + c0) = xs;
  }
}

// ---------------------------------------------------------------------------
// Attention per (h,n): o = exp(cs)*(q@X) + tril-gated (q@k^T)@v + alpha*v.
// ---------------------------------------------------------------------------
__global__ __launch_bounds__(256) void attn_kernel(
    const float* __restrict__ qs, const float* __restrict__ ks,
    const float* __restrict__ vs, const float* __restrict__ X,
    const float* __restrict__ cs, const float* __restrict__ beta,
    const float* __restrict__ alpha, float* __restrict__ o) {
  int bid = blockIdx.x;             // h*16+n
  int h = bid >> 4, n = bid & 15;
  int hk = h >> 1;
  __shared__ float qb[CSZ * HDIM];
  __shared__ float wb[CSZ * HDIM];
  int tid = threadIdx.x;

  for (int l = tid; l < CSZ * HDIM; l += 256) {
    int c = l >> 7, d = l & 127;
    qb[l] = qs[(size_t)(n * CSZ + c) * (NHQ * HDIM) + h * HDIM + d];
  }
  __syncthreads();

  int c = tid >> 2;
  int e0 = (tid & 3) << 5;
  float acc[32];
#pragma unroll
  for (int j = 0; j < 32; j++) acc[j] = 0.f;

  size_t xbase = (size_t)bid << 14;
  for (int d0 = 0; d0 < 128; d0 += 16) {
    __syncthreads();
    for (int l = tid; l < 16 * 128; l += 256)
      wb[l] = X[xbase + d0 * 128 + l];
    __syncthreads();
#pragma unroll
    for (int dd = 0; dd < 16; ++dd) {
      float a = qb[c * 128 + d0 + dd];
      const float4* xr = (const float4*)(wb + dd * 128 + e0);
#pragma unroll
      for (int j4 = 0; j4 < 8; ++j4) {
        float4 xv = xr[j4];
        acc[j4*4+0] = fmaf(a, xv.x, acc[j4*4+0]);
        acc[j4*4+1] = fmaf(a, xv.y, acc[j4*4+1]);
        acc[j4*4+2] = fmaf(a, xv.z, acc[j4*4+2]);
        acc[j4*4+3] = fmaf(a, xv.w, acc[j4*4+3]);
      }
    }
  }
  float csc = cs[bid * CSZ + c];
  float esc = expf(csc);
#pragma unroll
  for (int j = 0; j < 32; j++) acc[j] *= esc;

  __syncthreads();
  for (int l = tid; l < CSZ * HDIM; l += 256) {
    int cc = l >> 7, d = l & 127;
    wb[l] = ks[(size_t)(n * CSZ + cc) * (NHK * HDIM) + hk * HDIM + d];
  }
  __syncthreads();
  int jj0 = (tid & 3) << 4;
  float sreg[16];
#pragma unroll
  for (int j = 0; j < 16; ++j) {
    int jc = jj0 + j;
    float dotv = 0.f;
    if (jc <= c) {
      const float4* qr = (const float4*)(qb + c * 128);
      const float4* kr = (const float4*)(wb + jc * 128);
#pragma unroll
      for (int d4 = 0; d4 < 32; ++d4) {
        float4 qv = qr[d4];
        float4 kv = kr[d4];
        dotv = fmaf(qv.x, kv.x, dotv);
        dotv = fmaf(qv.y, kv.y, dotv);
        dotv = fmaf(qv.z, kv.z, dotv);
        dotv = fmaf(qv.w, kv.w, dotv);
      }
      float csj = cs[bid * CSZ + jc];
      float bj = beta[(n * CSZ + jc) * NHQ + h];
      dotv *= expf(csc - csj) * bj;
    }
    sreg[j] = dotv;
  }
  __syncthreads();
#pragma unroll
  for (int j = 0; j < 16; ++j) qb[c * 65 + jj0 + j] = sreg[j];
  for (int l = tid; l < CSZ * HDIM; l += 256) {
    int cc = l >> 7, d = l & 127;
    wb[l] = vs[(size_t)(n * CSZ + cc) * (NHK * HDIM) + hk * HDIM + d];
  }
  __syncthreads();

#pragma unroll 4
  for (int jc = 0; jc < CSZ; ++jc) {
    float sv = qb[c * 65 + jc];
    const float4* vr = (const float4*)(wb + jc * 128 + e0);
#pragma unroll
    for (int j4 = 0; j4 < 8; ++j4) {
      float4 vv = vr[j4];
      acc[j4*4+0] = fmaf(sv, vv.x, acc[j4*4+0]);
      acc[j4*4+1] = fmaf(sv, vv.y, acc[j4*4+1]);
      acc[j4*4+2] = fmaf(sv, vv.z, acc[j4*4+2]);
      acc[j4*4+3] = fmaf(sv, vv.w, acc[j4*4+3]);
    }
  }
  float al = alpha[(n * CSZ + c) * NHQ + h];
  {
    const float4* vr = (const float4*)(wb + c * 128 + e0);
#pragma unroll
    for (int j4 = 0; j4 < 8; ++j4) {
      float4 vv = vr[j4];
      acc[j4*4+0] = fmaf(al, vv.x, acc[j4*4+0]);
      acc[j4*4+1] = fmaf(al, vv.y, acc[j4*4+1]);
      acc[j4*4+2] = fmaf(al, vv.z, acc[j4*4+2]);
      acc[j4*4+3] = fmaf(al, vv.w, acc[j4*4+3]);
    }
  }
  size_t ob = ((size_t)(n * CSZ + c) * NHQ + h) * HDIM + e0;
#pragma unroll
  for (int j4 = 0; j4 < 8; ++j4) {
    float4 st = make_float4(acc[j4*4+0], acc[j4*4+1], acc[j4*4+2], acc[j4*4+3]);
    *(float4*)(o + ob + j4 * 4) = st;
  }
}

// ---------------------------------------------------------------------------
// Gated RMSNorm -> bf16 output.
// ---------------------------------------------------------------------------
__global__ __launch_bounds__(256) void rmsnorm_kernel(
    const float* __restrict__ o, const float* __restrict__ xg,
    const float* __restrict__ norm_w, unsigned short* __restrict__ onorm) {
  int wave = threadIdx.x >> 6, lane = threadIdx.x & 63;
  int row = blockIdx.x * 4 + wave;
  size_t base = (size_t)row * HDIM;
  float v0 = o[base + lane], v1 = o[base + lane + 64];
  float ss = fmaf(v0, v0, v1 * v1);
#pragma unroll
  for (int off = 32; off; off >>= 1) ss += __shfl_down(ss, off);
  ss = __shfl(ss, 0);
  float rinv = rsqrtf(ss * (1.f / 128.f) + 1e-6f);
  float g0 = xg[base + lane], g1 = xg[base + lane + 64];
  float s0 = g0 / (1.f + expf(-g0));
  float s1 = g1 / (1.f + expf(-g1));
  onorm[base + lane]      = f2bf(v0 * rinv * norm_w[lane] * s0);
  onorm[base + lane + 64] = f2bf(v1 * rinv * norm_w[lane + 64] * s1);
}

// ---------------------------------------------------------------------------
extern "C" void kernel_launch(void* const* d_in, const int* in_sizes, int n_in,
                              void* d_out, int out_size, void* d_ws,
                              size_t ws_size, hipStream_t stream) {
  (void)in_sizes; (void)n_in; (void)out_size; (void)ws_size;
  const float* x      = (const float*)d_in[0];
  const float* Wq     = (const float*)d_in[1];
  const float* Wk     = (const float*)d_in[2];
  const float* Wv     = (const float*)d_in[3];
  const float* convq  = (const float*)d_in[4];
  const float* convk  = (const float*)d_in[5];
  const float* convv  = (const float*)d_in[6];
  const float* Wa     = (const float*)d_in[7];
  const float* A_log  = (const float*)d_in[8];
  const float* dtb    = (const float*)d_in[9];
  const float* Wb     = (const float*)d_in[10];
  const float* bbv    = (const float*)d_in[11];
  const float* Wal    = (const float*)d_in[12];
  const float* balv   = (const float*)d_in[13];
  const float* Wg     = (const float*)d_in[14];
  const float* norm_w = (const float*)d_in[15];
  const float* Wo     = (const float*)d_in[16];
  float* out = (float*)d_out;

  // workspace layout (float slots), ~84 MB total
  float* p = (float*)d_ws;
  float* xq    = p; p += 2097152;   // [L,2048]; reused as ob (attn out)
  float* xk    = p; p += 1048576;
  float* xv    = p; p += 1048576;   // reused as onorm16 (bf16) after conv
  float* xg    = p; p += 2097152;
  float* qs    = p; p += 2097152;
  float* ks2   = p; p += 1048576;
  float* vs2   = p; p += 1048576;
  float* glog  = p; p += 16384;
  float* beta  = p; p += 16384;
  float* alpha = p; p += 16384;
  float* csb   = p; p += 16384;
  float* wend  = p; p += 16384;
  float* dHn   = p; p += 4194304;   // -> A after scan
  float* dBn   = p; p += 4194304;   // -> B0 -> X in place
  unsigned short* xb16 = (unsigned short*)p; p += 1048576;  // x as bf16
  unsigned short* Wt   = (unsigned short*)p; p += 2097152;  // per-gemm Wt bf16

  float* ob = xq;                       // alias (free after conv)
  unsigned short* onorm16 = (unsigned short*)xv;  // alias (free after conv)

  dim3 blk(256);
  // x -> bf16
  castbf<<<2048, blk, 0, stream>>>(x, xb16);
  // projections via bf16 MFMA (Wt buffer reused serially on the stream)
  tcast<<<dim3(64, 64), blk, 0, stream>>>(Wq, Wt, 2048, 2048);
  gemm_bf16<<<dim3(32, 8), blk, 0, stream>>>(xb16, Wt, xq, 1024, 2048, 2048);
  tcast<<<dim3(32, 64), blk, 0, stream>>>(Wk, Wt, 2048, 1024);
  gemm_bf16<<<dim3(16, 8), blk, 0, stream>>>(xb16, Wt, xk, 1024, 1024, 2048);
  tcast<<<dim3(32, 64), blk, 0, stream>>>(Wv, Wt, 2048, 1024);
  gemm_bf16<<<dim3(16, 8), blk, 0, stream>>>(xb16, Wt, xv, 1024, 1024, 2048);
  tcast<<<dim3(64, 64), blk, 0, stream>>>(Wg, Wt, 2048, 2048);
  gemm_bf16<<<dim3(32, 8), blk, 0, stream>>>(xb16, Wt, xg, 1024, 2048, 2048);
  // causal conv + silu (q scaled by HD^-0.5)
  conv_silu<<<8192, blk, 0, stream>>>(xq, convq, qs, 2048, 0.08838834764831845f);
  conv_silu<<<4096, blk, 0, stream>>>(xk, convk, ks2, 1024, 1.0f);
  conv_silu<<<4096, blk, 0, stream>>>(xv, convv, vs2, 1024, 1.0f);
  // gates (fused skinny projections, f32) + cumulative decay
  gates_fused<<<1024, blk, 0, stream>>>(x, Wa, Wb, Wal, A_log, dtb, bbv, balv,
                                        glog, beta, alpha);
  cumsum_kernel<<<1, blk, 0, stream>>>(glog, beta, csb, wend);
  // gram increments, scan, Chebyshev
  dhb_kernel<<<256, blk, 0, stream>>>(ks2, vs2, wend, dHn, dBn);
  scan_kernel<<<1024, blk, 0, stream>>>(dHn, dBn, csb);
  cheb_kernel<<<256, dim3(512), 0, stream>>>(dHn, dBn);
  // attention
  attn_kernel<<<256, blk, 0, stream>>>(qs, ks2, vs2, dBn, csb, beta, alpha, ob);
  // gated RMSNorm (bf16 out) + output projection via MFMA
  rmsnorm_kernel<<<4096, blk, 0, stream>>>(ob, xg, norm_w, onorm16);
  tcast<<<dim3(64, 64), blk, 0, stream>>>(Wo, Wt, 2048, 2048);
  gemm_bf16<<<dim3(32, 8), blk, 0, stream>>>(onorm16, Wt, out, 1024, 2048, 2048);
}

// Round 4
// 571.566 us; speedup vs baseline: 7.9337x; 1.9313x over previous
//
#include <hip/hip_runtime.h>
#include <math.h>

// GatedKalmaNet: B=1, L=1024, D=2048, HQ=16, HK=8, HD=128, CONV=4, CHUNK=64,
// Nc=16, NUM_ITER=30, RIDGE=0.02, EPS=1e-6.

#define LSEQ 1024
#define DM   2048
#define NHQ  16
#define NHK  8
#define HDIM 128
#define NCH  16
#define CSZ  64

typedef __attribute__((ext_vector_type(8))) short short8;
typedef __attribute__((ext_vector_type(4))) float floatx4;

// f32 -> bf16 RNE
__device__ __forceinline__ unsigned short f2bf(float f) {
  unsigned int u = __float_as_uint(f);
  u += 0x7fffu + ((u >> 16) & 1u);
  return (unsigned short)(u >> 16);
}
__device__ __forceinline__ float bf2f(unsigned short u) {
  return __uint_as_float(((unsigned int)u) << 16);
}

// ---------------------------------------------------------------------------
// Elementwise f32 -> bf16 cast (4 elems/thread).
// ---------------------------------------------------------------------------
__global__ __launch_bounds__(256) void castbf(
    const float* __restrict__ a, unsigned short* __restrict__ o) {
  int i = blockIdx.x * 256 + threadIdx.x;
  float4 v = ((const float4*)a)[i];
  ushort4 u;
  u.x = f2bf(v.x); u.y = f2bf(v.y); u.z = f2bf(v.z); u.w = f2bf(v.w);
  ((ushort4*)o)[i] = u;
}

// ---------------------------------------------------------------------------
// Transpose-cast: W[K][N] f32 -> Wt[N][K] bf16.  32x32 LDS tiles.
// ---------------------------------------------------------------------------
__global__ __launch_bounds__(256) void tcast(
    const float* __restrict__ W, unsigned short* __restrict__ Wt,
    int K, int N) {
  __shared__ float t[32][33];
  int bn = blockIdx.x, bk = blockIdx.y;
  int tid = threadIdx.x;
  int r = tid >> 5, c = tid & 31;
#pragma unroll
  for (int i = 0; i < 4; ++i)
    t[r + i * 8][c] = W[(size_t)(bk * 32 + r + i * 8) * N + bn * 32 + c];
  __syncthreads();
#pragma unroll
  for (int i = 0; i < 4; ++i)
    Wt[(size_t)(bn * 32 + r + i * 8) * K + bk * 32 + c] =
        f2bf(t[c][r + i * 8]);
}

// ---------------------------------------------------------------------------
// bf16 MFMA GEMM: C[M,N](f32) = A[M,K](bf16) @ Bt[N,K](bf16)^T.
// BM=128 BN=64 BK=64; 256 thr = 4 waves (2x2); wave tile 64x32.
// ---------------------------------------------------------------------------
__global__ __launch_bounds__(256) void gemm_bf16(
    const unsigned short* __restrict__ A, const unsigned short* __restrict__ Bt,
    float* __restrict__ C, int M, int N, int K) {
  __shared__ unsigned short As[128 * 72];
  __shared__ unsigned short Bs[64 * 72];
  int tid = threadIdx.x;
  int wave = tid >> 6, lane = tid & 63;
  int ln = lane & 15, hi = lane >> 4;
  int wm = wave & 1, wn = wave >> 1;
  int m0 = blockIdx.y * 128, n0 = blockIdx.x * 64;

  floatx4 acc[4][2];
#pragma unroll
  for (int mt = 0; mt < 4; ++mt)
#pragma unroll
    for (int nt = 0; nt < 2; ++nt) acc[mt][nt] = (floatx4)(0.f);

  for (int k0 = 0; k0 < K; k0 += 64) {
#pragma unroll
    for (int g = 0; g < 4; ++g) {
      int l = tid + g * 256;
      int m = l >> 3, go = l & 7;
      uint4 v = *(const uint4*)(A + (size_t)(m0 + m) * K + k0 + go * 8);
      *(uint4*)(As + m * 72 + go * 8) = v;
    }
#pragma unroll
    for (int g = 0; g < 2; ++g) {
      int l = tid + g * 256;
      int n = l >> 3, go = l & 7;
      uint4 v = *(const uint4*)(Bt + (size_t)(n0 + n) * K + k0 + go * 8);
      *(uint4*)(Bs + n * 72 + go * 8) = v;
    }
    __syncthreads();
#pragma unroll
    for (int kb = 0; kb < 2; ++kb) {
      short8 a[4], b[2];
#pragma unroll
      for (int mt = 0; mt < 4; ++mt)
        a[mt] = *(const short8*)(As + (wm * 64 + mt * 16 + ln) * 72 + kb * 32 + hi * 8);
#pragma unroll
      for (int nt = 0; nt < 2; ++nt)
        b[nt] = *(const short8*)(Bs + (wn * 32 + nt * 16 + ln) * 72 + kb * 32 + hi * 8);
#pragma unroll
      for (int mt = 0; mt < 4; ++mt)
#pragma unroll
        for (int nt = 0; nt < 2; ++nt)
          acc[mt][nt] = __builtin_amdgcn_mfma_f32_16x16x32_bf16(
              a[mt], b[nt], acc[mt][nt], 0, 0, 0);
    }
    __syncthreads();
  }
#pragma unroll
  for (int mt = 0; mt < 4; ++mt)
#pragma unroll
    for (int nt = 0; nt < 2; ++nt) {
      int col = n0 + wn * 32 + nt * 16 + ln;
      int rowb = m0 + wm * 64 + mt * 16 + hi * 4;
#pragma unroll
      for (int r = 0; r < 4; ++r)
        C[(size_t)(rowb + r) * N + col] = acc[mt][nt][r];
    }
}

// ---------------------------------------------------------------------------
// Causal depthwise conv (K=4) + silu (+ scale).  x:[L,*] row stride instride.
// ---------------------------------------------------------------------------
__global__ __launch_bounds__(256) void conv_silu(
    const float* __restrict__ xin, const float* __restrict__ w,
    float* __restrict__ outp, int instride, int nch, float scale) {
  int idx = blockIdx.x * 256 + threadIdx.x;
  int t = idx / nch, ch = idx - t * nch;
  float acc = 0.f;
#pragma unroll
  for (int j = 0; j < 4; ++j) {
    int tt = t + j - 3;
    float xv = (tt >= 0) ? xin[(size_t)tt * instride + ch] : 0.f;
    acc = fmaf(xv, w[ch * 4 + j], acc);
  }
  float sv = acc / (1.f + expf(-acc));
  outp[idx] = sv * scale;
}

// ---------------------------------------------------------------------------
// Fused skinny projections + gate nonlinearities.  One block per timestep.
// ---------------------------------------------------------------------------
__global__ __launch_bounds__(256) void gates_fused(
    const float* __restrict__ x, const float* __restrict__ Wa,
    const float* __restrict__ Wb, const float* __restrict__ Wal,
    const float* __restrict__ A_log, const float* __restrict__ dtb,
    const float* __restrict__ bbv, const float* __restrict__ balv,
    float* __restrict__ glog, float* __restrict__ beta,
    float* __restrict__ alpha) {
  int t = blockIdx.x;
  __shared__ float xr[2048];
  __shared__ float part[256];
  int tid = threadIdx.x;
  for (int i = tid; i < 512; i += 256)
    ((float4*)xr)[i] = ((const float4*)(x + (size_t)t * 2048))[i];
  __syncthreads();
  int o = tid >> 2, p = tid & 3;
  float s = 0.f;
  if (o < 48) {
    const float* W = (o < 16) ? Wa : (o < 32) ? Wb : Wal;
    int h = o & 15;
    int k0 = p * 512;
    for (int k = k0; k < k0 + 512; ++k) s = fmaf(xr[k], W[k * 16 + h], s);
  }
  part[tid] = s;
  __syncthreads();
  if (o < 48 && p == 0) {
    float dot = part[tid] + part[tid + 1] + part[tid + 2] + part[tid + 3];
    int h = o & 15;
    if (o < 16) {
      float za = dot + dtb[h];
      float sp = fmaxf(za, 0.f) + log1pf(expf(-fabsf(za)));
      glog[t * 16 + h] = -expf(A_log[h]) * sp;
    } else if (o < 32) {
      beta[t * 16 + h] = 1.f / (1.f + expf(-(dot + bbv[h])));
    } else {
      alpha[t * 16 + h] = 1.f / (1.f + expf(-(dot + balv[h])));
    }
  }
}

// ---------------------------------------------------------------------------
// Per-(h,n) inclusive cumsum of glog within chunk + w_end = exp(G-cs)*beta.
// ---------------------------------------------------------------------------
__global__ __launch_bounds__(256) void cumsum_kernel(
    const float* __restrict__ glog, const float* __restrict__ beta,
    float* __restrict__ cs, float* __restrict__ wend) {
  int idx = threadIdx.x;            // h*16+n
  int n = idx & 15;
  float acc = 0.f;
  for (int c = 0; c < CSZ; ++c) {
    acc += glog[(n * CSZ + c) * NHQ + (idx >> 4)];
    cs[idx * CSZ + c] = acc;
  }
  float G = acc;
  for (int c = 0; c < CSZ; ++c) {
    wend[idx * CSZ + c] =
        expf(G - cs[idx * CSZ + c]) * beta[(n * CSZ + c) * NHQ + (idx >> 4)];
  }
}

// ---------------------------------------------------------------------------
// Gram increments per (h,n): dH = sum_c w*k*k^T (exactly symmetric), dB = w*k*v^T
// ---------------------------------------------------------------------------
__global__ __launch_bounds__(256) void dhb_kernel(
    const float* __restrict__ ks, const float* __restrict__ vs,
    const float* __restrict__ wend, float* __restrict__ dH,
    float* __restrict__ dB) {
  int bid = blockIdx.x;             // h*16+n
  int h = bid >> 4, n = bid & 15;
  int hk = h >> 1;
  __shared__ float kt[CSZ][HDIM];
  __shared__ float vt[CSZ][HDIM];
  int tid = threadIdx.x;
  for (int l = tid; l < CSZ * HDIM; l += 256) {
    int c = l >> 7, d = l & 127;
    size_t g = (size_t)(n * CSZ + c) * (NHK * HDIM) + hk * HDIM + d;
    kt[c][d] = ks[g];
    vt[c][d] = vs[g];
  }
  __syncthreads();
  int r = tid >> 1;
  int e0 = (tid & 1) << 6;
  float accH[64], accB[64];
#pragma unroll
  for (int j = 0; j < 64; j++) { accH[j] = 0.f; accB[j] = 0.f; }
  for (int c = 0; c < CSZ; ++c) {
    float w = wend[bid * CSZ + c];
    float kr = kt[c][r];
    float a = w * kr;
    const float4* kr4 = (const float4*)(&kt[c][e0]);
    const float4* vr4 = (const float4*)(&vt[c][e0]);
#pragma unroll
    for (int j4 = 0; j4 < 16; ++j4) {
      float4 kv = kr4[j4];
      float4 vv = vr4[j4];
      accH[j4*4+0] = fmaf(w, kr * kv.x, accH[j4*4+0]);
      accH[j4*4+1] = fmaf(w, kr * kv.y, accH[j4*4+1]);
      accH[j4*4+2] = fmaf(w, kr * kv.z, accH[j4*4+2]);
      accH[j4*4+3] = fmaf(w, kr * kv.w, accH[j4*4+3]);
      accB[j4*4+0] = fmaf(a, vv.x, accB[j4*4+0]);
      accB[j4*4+1] = fmaf(a, vv.y, accB[j4*4+1]);
      accB[j4*4+2] = fmaf(a, vv.z, accB[j4*4+2]);
      accB[j4*4+3] = fmaf(a, vv.w, accB[j4*4+3]);
    }
  }
  size_t base = ((size_t)bid * HDIM + r) * HDIM + e0;
#pragma unroll
  for (int j = 0; j < 64; j++) { dH[base + j] = accH[j]; dB[base + j] = accB[j]; }
}

// ---------------------------------------------------------------------------
// Inter-chunk scan (in-place): store state at chunk start; A gets +ridge diag.
// ---------------------------------------------------------------------------
__global__ __launch_bounds__(256) void scan_kernel(
    float* __restrict__ dH, float* __restrict__ dB,
    const float* __restrict__ cs) {
  int idx = blockIdx.x * 256 + threadIdx.x;  // h*16384 + de
  int h = idx >> 14, de = idx & 16383;
  float Hs = 0.f, Bs = 0.f;
  bool diag = ((de % 129) == 0);
#pragma unroll 1
  for (int n = 0; n < NCH; ++n) {
    size_t off = ((size_t)(h * 16 + n) << 14) + de;
    float dh = dH[off], db = dB[off];
    dH[off] = diag ? (Hs + 0.02f) : Hs;
    dB[off] = Bs;
    float g = expf(cs[(h * 16 + n) * CSZ + (CSZ - 1)]);
    Hs = fmaf(g, Hs, dh);
    Bs = fmaf(g, Bs, db);
  }
}

// ---------------------------------------------------------------------------
// In-place A (f32, 128x128 per matrix) -> split bf16 MFMA fragments + trace.
// Frag layout per matrix: hi[16384] then lo[16384] bf16; frag id = mt*4+kt,
// element ((frag*64 + (q*16+ln)) * 8 + j) holds A[mt*16+ln][kt*32+q*8+j].
// ---------------------------------------------------------------------------
__global__ __launch_bounds__(256) void afrag_kernel(
    float* __restrict__ Aall, float* __restrict__ traces) {
  int bid = blockIdx.x;
  float* Ag = Aall + ((size_t)bid << 14);
  __shared__ float As[16384];
  int tid = threadIdx.x;
  for (int i = tid; i < 4096; i += 256)
    ((float4*)As)[i] = ((const float4*)Ag)[i];
  __syncthreads();
  if (tid < 64) {
    float tv = As[tid * 129] + As[(tid + 64) * 129];
#pragma unroll
    for (int off = 32; off; off >>= 1) tv += __shfl_down(tv, off);
    if (tid == 0) traces[bid] = tv;
  }
  unsigned short* Ah = (unsigned short*)Ag;
  unsigned short* Al = Ah + 16384;
#pragma unroll
  for (int c8 = 0; c8 < 8; ++c8) {
    int s0 = tid * 64 + c8 * 8;
    int frag = s0 >> 9, mlane = (s0 >> 3) & 63;
    int m = ((frag >> 2) << 4) + (mlane & 15);
    int k = ((frag & 3) << 5) + ((mlane >> 4) << 3);
    unsigned short hi[8], lo[8];
#pragma unroll
    for (int j = 0; j < 8; ++j) {
      float a = As[m * 128 + k + j];
      unsigned short h = f2bf(a);
      hi[j] = h;
      lo[j] = f2bf(a - bf2f(h));
    }
    *(uint4*)(Ah + s0) = *(uint4*)hi;
    *(uint4*)(Al + s0) = *(uint4*)lo;
  }
}

// ---------------------------------------------------------------------------
// Chebyshev solve via MFMA.  One block (512 thr, 8 waves) per (h,n) matrix.
// A held in registers as split-bf16 fragments (per wave: its 16-row m-tile).
// dvec: single-bf16, XOR-swizzled LDS [n][k] (32 KB); x,r f32 in registers.
// Consistency: x accumulates exactly the quantized dvec the MFMA multiplies.
// ---------------------------------------------------------------------------
__global__ __launch_bounds__(512) void cheb_kernel(
    const unsigned short* __restrict__ Afrag, const float* __restrict__ traces,
    float* __restrict__ Ball) {
  int bid = blockIdx.x;
  const unsigned short* __restrict__ Ah = Afrag + ((size_t)bid << 15);
  float* __restrict__ Bg = Ball + ((size_t)bid << 14);
  __shared__ unsigned short dT[16384];   // 32 KB, rows n, chunk-swizzled k
  int tid = threadIdx.x;
  int w = tid >> 6, lane = tid & 63;
  int ln = lane & 15, q = lane >> 4;

  float lmax = traces[bid];
  const float lmin = 0.02f;
  float theta = 0.5f * (lmax + lmin);
  float delta = 0.5f * (lmax - lmin);
  float sigma1 = theta / delta;
  float rho = delta / theta;
  float invtheta = 1.f / theta;

  // A fragments for this wave's m-tile, all 4 k-tiles, hi+lo: in registers.
  short8 afr[4][2];
#pragma unroll
  for (int kt = 0; kt < 4; ++kt) {
    afr[kt][0] = *(const short8*)(Ah + (((w * 4 + kt) * 64 + lane) << 3));
    afr[kt][1] = *(const short8*)(Ah + 16384 + (((w * 4 + kt) * 64 + lane) << 3));
  }

  int cw = (w << 1) + (q >> 1);        // write chunk index (k = w*16+q*4+reg)
  int j0 = (q & 1) << 2;               // offset within chunk

  float xx[8][4], rr[8][4], dd[8][4];
#pragma unroll
  for (int nt = 0; nt < 8; ++nt) {
    int n = nt * 16 + ln;
    ushort4 pack;
    unsigned short* pp = (unsigned short*)&pack;
#pragma unroll
    for (int rg = 0; rg < 4; ++rg) {
      float b = Bg[(w * 16 + q * 4 + rg) * 128 + n];
      rr[nt][rg] = b;
      xx[nt][rg] = 0.f;
      unsigned short dq = f2bf(b * invtheta);
      dd[nt][rg] = bf2f(dq);
      pp[rg] = dq;
    }
    *(ushort4*)(dT + n * 128 + ((cw ^ ln) << 3) + j0) = pack;
  }
  __syncthreads();

#pragma unroll 1
  for (int it = 0; it < 30; ++it) {
    floatx4 acc[8];
#pragma unroll
    for (int nt = 0; nt < 8; ++nt) acc[nt] = (floatx4)(0.f);
#pragma unroll
    for (int kt = 0; kt < 4; ++kt) {
      short8 df[8];
#pragma unroll
      for (int nt = 0; nt < 8; ++nt)
        df[nt] = *(const short8*)(dT + (nt * 16 + ln) * 128 +
                                  (((kt * 4 + q) ^ ln) << 3));
#pragma unroll
      for (int nt = 0; nt < 8; ++nt) {
        acc[nt] = __builtin_amdgcn_mfma_f32_16x16x32_bf16(
            afr[kt][0], df[nt], acc[nt], 0, 0, 0);
        acc[nt] = __builtin_amdgcn_mfma_f32_16x16x32_bf16(
            afr[kt][1], df[nt], acc[nt], 0, 0, 0);
      }
    }
    float rho_n = 1.f / (2.f * sigma1 - rho);
    float c1s = rho_n * rho;
    float c2s = 2.f * rho_n / delta;
    __syncthreads();                    // all dT reads done
#pragma unroll
    for (int nt = 0; nt < 8; ++nt) {
      int n = nt * 16 + ln;
      ushort4 pack;
      unsigned short* pp = (unsigned short*)&pack;
#pragma unroll
      for (int rg = 0; rg < 4; ++rg) {
        xx[nt][rg] += dd[nt][rg];
        rr[nt][rg] -= acc[nt][rg];
        float dn = fmaf(c1s, dd[nt][rg], c2s * rr[nt][rg]);
        unsigned short dq = f2bf(dn);
        dd[nt][rg] = bf2f(dq);
        pp[rg] = dq;
      }
      *(ushort4*)(dT + n * 128 + ((cw ^ ln) << 3) + j0) = pack;
    }
    rho = rho_n;
    __syncthreads();
  }
#pragma unroll
  for (int nt = 0; nt < 8; ++nt)
#pragma unroll
    for (int rg = 0; rg < 4; ++rg)
      Bg[(w * 16 + q * 4 + rg) * 128 + nt * 16 + ln] = xx[nt][rg];
}

// ---------------------------------------------------------------------------
// Attention per (h,n): o = exp(cs)*(q@X) + tril-gated (q@k^T)@v + alpha*v.
// ---------------------------------------------------------------------------
__global__ __launch_bounds__(256) void attn_kernel(
    const float* __restrict__ qs, const float* __restrict__ ks,
    const float* __restrict__ vs, const float* __restrict__ X,
    const float* __restrict__ cs, const float* __restrict__ beta,
    const float* __restrict__ alpha, float* __restrict__ o) {
  int bid = blockIdx.x;             // h*16+n
  int h = bid >> 4, n = bid & 15;
  int hk = h >> 1;
  __shared__ float qb[CSZ * HDIM];
  __shared__ float wb[CSZ * HDIM];
  int tid = threadIdx.x;

  for (int l = tid; l < CSZ * HDIM; l += 256) {
    int c = l >> 7, d = l & 127;
    qb[l] = qs[(size_t)(n * CSZ + c) * (NHQ * HDIM) + h * HDIM + d];
  }
  __syncthreads();

  int c = tid >> 2;
  int e0 = (tid & 3) << 5;
  float acc[32];
#pragma unroll
  for (int j = 0; j < 32; j++) acc[j] = 0.f;

  size_t xbase = (size_t)bid << 14;
  for (int d0 = 0; d0 < 128; d0 += 16) {
    __syncthreads();
    for (int l = tid; l < 16 * 128; l += 256)
      wb[l] = X[xbase + d0 * 128 + l];
    __syncthreads();
#pragma unroll
    for (int dd = 0; dd < 16; ++dd) {
      float a = qb[c * 128 + d0 + dd];
      const float4* xr = (const float4*)(wb + dd * 128 + e0);
#pragma unroll
      for (int j4 = 0; j4 < 8; ++j4) {
        float4 xv = xr[j4];
        acc[j4*4+0] = fmaf(a, xv.x, acc[j4*4+0]);
        acc[j4*4+1] = fmaf(a, xv.y, acc[j4*4+1]);
        acc[j4*4+2] = fmaf(a, xv.z, acc[j4*4+2]);
        acc[j4*4+3] = fmaf(a, xv.w, acc[j4*4+3]);
      }
    }
  }
  float csc = cs[bid * CSZ + c];
  float esc = expf(csc);
#pragma unroll
  for (int j = 0; j < 32; j++) acc[j] *= esc;

  __syncthreads();
  for (int l = tid; l < CSZ * HDIM; l += 256) {
    int cc = l >> 7, d = l & 127;
    wb[l] = ks[(size_t)(n * CSZ + cc) * (NHK * HDIM) + hk * HDIM + d];
  }
  __syncthreads();
  int jj0 = (tid & 3) << 4;
  float sreg[16];
#pragma unroll
  for (int j = 0; j < 16; ++j) {
    int jc = jj0 + j;
    float dotv = 0.f;
    if (jc <= c) {
      const float4* qr = (const float4*)(qb + c * 128);
      const float4* kr = (const float4*)(wb + jc * 128);
#pragma unroll
      for (int d4 = 0; d4 < 32; ++d4) {
        float4 qv = qr[d4];
        float4 kv = kr[d4];
        dotv = fmaf(qv.x, kv.x, dotv);
        dotv = fmaf(qv.y, kv.y, dotv);
        dotv = fmaf(qv.z, kv.z, dotv);
        dotv = fmaf(qv.w, kv.w, dotv);
      }
      float csj = cs[bid * CSZ + jc];
      float bj = beta[(n * CSZ + jc) * NHQ + h];
      dotv *= expf(csc - csj) * bj;
    }
    sreg[j] = dotv;
  }
  __syncthreads();
#pragma unroll
  for (int j = 0; j < 16; ++j) qb[c * 65 + jj0 + j] = sreg[j];
  for (int l = tid; l < CSZ * HDIM; l += 256) {
    int cc = l >> 7, d = l & 127;
    wb[l] = vs[(size_t)(n * CSZ + cc) * (NHK * HDIM) + hk * HDIM + d];
  }
  __syncthreads();

#pragma unroll 4
  for (int jc = 0; jc < CSZ; ++jc) {
    float sv = qb[c * 65 + jc];
    const float4* vr = (const float4*)(wb + jc * 128 + e0);
#pragma unroll
    for (int j4 = 0; j4 < 8; ++j4) {
      float4 vv = vr[j4];
      acc[j4*4+0] = fmaf(sv, vv.x, acc[j4*4+0]);
      acc[j4*4+1] = fmaf(sv, vv.y, acc[j4*4+1]);
      acc[j4*4+2] = fmaf(sv, vv.z, acc[j4*4+2]);
      acc[j4*4+3] = fmaf(sv, vv.w, acc[j4*4+3]);
    }
  }
  float al = alpha[(n * CSZ + c) * NHQ + h];
  {
    const float4* vr = (const float4*)(wb + c * 128 + e0);
#pragma unroll
    for (int j4 = 0; j4 < 8; ++j4) {
      float4 vv = vr[j4];
      acc[j4*4+0] = fmaf(al, vv.x, acc[j4*4+0]);
      acc[j4*4+1] = fmaf(al, vv.y, acc[j4*4+1]);
      acc[j4*4+2] = fmaf(al, vv.z, acc[j4*4+2]);
      acc[j4*4+3] = fmaf(al, vv.w, acc[j4*4+3]);
    }
  }
  size_t ob = ((size_t)(n * CSZ + c) * NHQ + h) * HDIM + e0;
#pragma unroll
  for (int j4 = 0; j4 < 8; ++j4) {
    float4 st = make_float4(acc[j4*4+0], acc[j4*4+1], acc[j4*4+2], acc[j4*4+3]);
    *(float4*)(o + ob + j4 * 4) = st;
  }
}

// ---------------------------------------------------------------------------
// Gated RMSNorm -> bf16 output.  g read from xall (cols 4096.., stride 6144).
// ---------------------------------------------------------------------------
__global__ __launch_bounds__(256) void rmsnorm_kernel(
    const float* __restrict__ o, const float* __restrict__ xall,
    const float* __restrict__ norm_w, unsigned short* __restrict__ onorm) {
  int wave = threadIdx.x >> 6, lane = threadIdx.x & 63;
  int row = blockIdx.x * 4 + wave;          // t*16 + h
  size_t base = (size_t)row * HDIM;
  size_t gbase = (size_t)(row >> 4) * 6144 + 4096 + (size_t)(row & 15) * HDIM;
  float v0 = o[base + lane], v1 = o[base + lane + 64];
  float ss = fmaf(v0, v0, v1 * v1);
#pragma unroll
  for (int off = 32; off; off >>= 1) ss += __shfl_down(ss, off);
  ss = __shfl(ss, 0);
  float rinv = rsqrtf(ss * (1.f / 128.f) + 1e-6f);
  float g0 = xall[gbase + lane], g1 = xall[gbase + lane + 64];
  float s0 = g0 / (1.f + expf(-g0));
  float s1 = g1 / (1.f + expf(-g1));
  onorm[base + lane]      = f2bf(v0 * rinv * norm_w[lane] * s0);
  onorm[base + lane + 64] = f2bf(v1 * rinv * norm_w[lane + 64] * s1);
}

// ---------------------------------------------------------------------------
extern "C" void kernel_launch(void* const* d_in, const int* in_sizes, int n_in,
                              void* d_out, int out_size, void* d_ws,
                              size_t ws_size, hipStream_t stream) {
  (void)in_sizes; (void)n_in; (void)out_size; (void)ws_size;
  const float* x      = (const float*)d_in[0];
  const float* Wq     = (const float*)d_in[1];
  const float* Wk     = (const float*)d_in[2];
  const float* Wv     = (const float*)d_in[3];
  const float* convq  = (const float*)d_in[4];
  const float* convk  = (const float*)d_in[5];
  const float* convv  = (const float*)d_in[6];
  const float* Wa     = (const float*)d_in[7];
  const float* A_log  = (const float*)d_in[8];
  const float* dtb    = (const float*)d_in[9];
  const float* Wb     = (const float*)d_in[10];
  const float* bbv    = (const float*)d_in[11];
  const float* Wal    = (const float*)d_in[12];
  const float* balv   = (const float*)d_in[13];
  const float* Wg     = (const float*)d_in[14];
  const float* norm_w = (const float*)d_in[15];
  const float* Wo     = (const float*)d_in[16];
  float* out = (float*)d_out;

  // workspace layout (float slots), ~88.5 MB total
  float* p = (float*)d_ws;
  float* xall  = p; p += 6291456;   // [L][6144]: q|k|v|g projections
  float* qs    = p; p += 2097152;
  float* ks2   = p; p += 1048576;   // + vs2 contiguous: reused as WtWo (bf16)
  float* vs2   = p; p += 1048576;
  float* ob    = p; p += 2097152;
  float* glog  = p; p += 16384;
  float* beta  = p; p += 16384;
  float* alpha = p; p += 16384;
  float* csb   = p; p += 16384;
  float* wend  = p; p += 16384;
  float* traces= p; p += 16384;     // 256 used
  float* dHn   = p; p += 4194304;   // -> A -> A-frags (bf16 hi/lo) in place
  float* dBn   = p; p += 4194304;   // -> B0 -> X in place
  unsigned short* xb16 = (unsigned short*)p; p += 1048576;

  unsigned short* WtAll = (unsigned short*)dHn;   // 24 MB over dHn+dBn (pre-dhb)
  unsigned short* WtWo  = (unsigned short*)ks2;   // 8 MB over ks2+vs2 (post-attn)
  unsigned short* onorm16 = xb16;                 // free after projections

  dim3 blk(256);
  castbf<<<2048, blk, 0, stream>>>(x, xb16);
  // batched projection: Wt rows: q 0-2047, k 2048-3071, v 3072-4095, g 4096-6143
  tcast<<<dim3(64, 64), blk, 0, stream>>>(Wq, WtAll, 2048, 2048);
  tcast<<<dim3(32, 64), blk, 0, stream>>>(Wk, WtAll + (size_t)2048 * 2048, 2048, 1024);
  tcast<<<dim3(32, 64), blk, 0, stream>>>(Wv, WtAll + (size_t)3072 * 2048, 2048, 1024);
  tcast<<<dim3(64, 64), blk, 0, stream>>>(Wg, WtAll + (size_t)4096 * 2048, 2048, 2048);
  gemm_bf16<<<dim3(96, 8), blk, 0, stream>>>(xb16, WtAll, xall, 1024, 6144, 2048);
  // causal conv + silu (q scaled by HD^-0.5)
  conv_silu<<<8192, blk, 0, stream>>>(xall, convq, qs, 6144, 2048, 0.08838834764831845f);
  conv_silu<<<4096, blk, 0, stream>>>(xall + 2048, convk, ks2, 6144, 1024, 1.0f);
  conv_silu<<<4096, blk, 0, stream>>>(xall + 3072, convv, vs2, 6144, 1024, 1.0f);
  // gates + cumulative decay
  gates_fused<<<1024, blk, 0, stream>>>(x, Wa, Wb, Wal, A_log, dtb, bbv, balv,
                                        glog, beta, alpha);
  cumsum_kernel<<<1, blk, 0, stream>>>(glog, beta, csb, wend);
  // gram increments (overwrites WtAll region), scan, A-frag prep, Chebyshev
  dhb_kernel<<<256, blk, 0, stream>>>(ks2, vs2, wend, dHn, dBn);
  scan_kernel<<<1024, blk, 0, stream>>>(dHn, dBn, csb);
  afrag_kernel<<<256, blk, 0, stream>>>(dHn, traces);
  cheb_kernel<<<256, dim3(512), 0, stream>>>((unsigned short*)dHn, traces, dBn);
  // attention
  attn_kernel<<<256, blk, 0, stream>>>(qs, ks2, vs2, dBn, csb, beta, alpha, ob);
  // gated RMSNorm (bf16 out) + output projection (WtWo overwrites ks2/vs2)
  rmsnorm_kernel<<<4096, blk, 0, stream>>>(ob, xall, norm_w, onorm16);
  tcast<<<dim3(64, 64), blk, 0, stream>>>(Wo, WtWo, 2048, 2048);
  gemm_bf16<<<dim3(32, 8), blk, 0, stream>>>(onorm16, WtWo, out, 1024, 2048, 2048);
}

// Round 6
// 512.878 us; speedup vs baseline: 8.8416x; 1.1144x over previous
//
#include <hip/hip_runtime.h>
#include <math.h>

// GatedKalmaNet: B=1, L=1024, D=2048, HQ=16, HK=8, HD=128, CONV=4, CHUNK=64,
// Nc=16, NUM_ITER=30, RIDGE=0.02, EPS=1e-6.

#define LSEQ 1024
#define DM   2048
#define NHQ  16
#define NHK  8
#define HDIM 128
#define NCH  16
#define CSZ  64

typedef __attribute__((ext_vector_type(8))) short short8;
typedef __attribute__((ext_vector_type(4))) float floatx4;

// f32 -> bf16 RNE
__device__ __forceinline__ unsigned short f2bf(float f) {
  unsigned int u = __float_as_uint(f);
  u += 0x7fffu + ((u >> 16) & 1u);
  return (unsigned short)(u >> 16);
}
__device__ __forceinline__ float bf2f(unsigned short u) {
  return __uint_as_float(((unsigned int)u) << 16);
}

// ---------------------------------------------------------------------------
// Elementwise f32 -> bf16 cast (4 elems/thread).
// ---------------------------------------------------------------------------
__global__ __launch_bounds__(256) void castbf(
    const float* __restrict__ a, unsigned short* __restrict__ o) {
  int i = blockIdx.x * 256 + threadIdx.x;
  float4 v = ((const float4*)a)[i];
  ushort4 u;
  u.x = f2bf(v.x); u.y = f2bf(v.y); u.z = f2bf(v.z); u.w = f2bf(v.w);
  ((ushort4*)o)[i] = u;
}

// ---------------------------------------------------------------------------
// Transpose-cast: W[K][N] f32 -> Wt[N][K] bf16.  32x32 LDS tiles.
// ---------------------------------------------------------------------------
__global__ __launch_bounds__(256) void tcast(
    const float* __restrict__ W, unsigned short* __restrict__ Wt,
    int K, int N) {
  __shared__ float t[32][33];
  int bn = blockIdx.x, bk = blockIdx.y;
  int tid = threadIdx.x;
  int r = tid >> 5, c = tid & 31;
#pragma unroll
  for (int i = 0; i < 4; ++i)
    t[r + i * 8][c] = W[(size_t)(bk * 32 + r + i * 8) * N + bn * 32 + c];
  __syncthreads();
#pragma unroll
  for (int i = 0; i < 4; ++i)
    Wt[(size_t)(bn * 32 + r + i * 8) * K + bk * 32 + c] =
        f2bf(t[c][r + i * 8]);
}

// ---------------------------------------------------------------------------
// bf16 MFMA GEMM: C[M,N](f32) = A[M,K](bf16) @ Bt[N,K](bf16)^T.
// BM=128 BN=64 BK=64; 256 thr = 4 waves (2x2); wave tile 64x32.
// ---------------------------------------------------------------------------
__global__ __launch_bounds__(256) void gemm_bf16(
    const unsigned short* __restrict__ A, const unsigned short* __restrict__ Bt,
    float* __restrict__ C, int M, int N, int K) {
  __shared__ unsigned short As[128 * 72];
  __shared__ unsigned short Bs[64 * 72];
  int tid = threadIdx.x;
  int wave = tid >> 6, lane = tid & 63;
  int ln = lane & 15, hi = lane >> 4;
  int wm = wave & 1, wn = wave >> 1;
  int m0 = blockIdx.y * 128, n0 = blockIdx.x * 64;

  floatx4 acc[4][2];
#pragma unroll
  for (int mt = 0; mt < 4; ++mt)
#pragma unroll
    for (int nt = 0; nt < 2; ++nt) acc[mt][nt] = (floatx4)(0.f);

  for (int k0 = 0; k0 < K; k0 += 64) {
#pragma unroll
    for (int g = 0; g < 4; ++g) {
      int l = tid + g * 256;
      int m = l >> 3, go = l & 7;
      uint4 v = *(const uint4*)(A + (size_t)(m0 + m) * K + k0 + go * 8);
      *(uint4*)(As + m * 72 + go * 8) = v;
    }
#pragma unroll
    for (int g = 0; g < 2; ++g) {
      int l = tid + g * 256;
      int n = l >> 3, go = l & 7;
      uint4 v = *(const uint4*)(Bt + (size_t)(n0 + n) * K + k0 + go * 8);
      *(uint4*)(Bs + n * 72 + go * 8) = v;
    }
    __syncthreads();
#pragma unroll
    for (int kb = 0; kb < 2; ++kb) {
      short8 a[4], b[2];
#pragma unroll
      for (int mt = 0; mt < 4; ++mt)
        a[mt] = *(const short8*)(As + (wm * 64 + mt * 16 + ln) * 72 + kb * 32 + hi * 8);
#pragma unroll
      for (int nt = 0; nt < 2; ++nt)
        b[nt] = *(const short8*)(Bs + (wn * 32 + nt * 16 + ln) * 72 + kb * 32 + hi * 8);
#pragma unroll
      for (int mt = 0; mt < 4; ++mt)
#pragma unroll
        for (int nt = 0; nt < 2; ++nt)
          acc[mt][nt] = __builtin_amdgcn_mfma_f32_16x16x32_bf16(
              a[mt], b[nt], acc[mt][nt], 0, 0, 0);
    }
    __syncthreads();
  }
#pragma unroll
  for (int mt = 0; mt < 4; ++mt)
#pragma unroll
    for (int nt = 0; nt < 2; ++nt) {
      int col = n0 + wn * 32 + nt * 16 + ln;
      int rowb = m0 + wm * 64 + mt * 16 + hi * 4;
#pragma unroll
      for (int r = 0; r < 4; ++r)
        C[(size_t)(rowb + r) * N + col] = acc[mt][nt][r];
    }
}

// ---------------------------------------------------------------------------
// Causal depthwise conv (K=4) + silu.  Three variants.
// ---------------------------------------------------------------------------
__device__ __forceinline__ float conv_core(
    const float* __restrict__ xin, const float* __restrict__ w,
    int idx, int instride, int nch, float scale) {
  int t = idx / nch, ch = idx - t * nch;
  float acc = 0.f;
#pragma unroll
  for (int j = 0; j < 4; ++j) {
    int tt = t + j - 3;
    float xv = (tt >= 0) ? xin[(size_t)tt * instride + ch] : 0.f;
    acc = fmaf(xv, w[ch * 4 + j], acc);
  }
  return acc / (1.f + expf(-acc)) * scale;
}

__global__ __launch_bounds__(256) void conv_silu(
    const float* __restrict__ xin, const float* __restrict__ w,
    float* __restrict__ outp, int instride, int nch, float scale) {
  int idx = blockIdx.x * 256 + threadIdx.x;
  outp[idx] = conv_core(xin, w, idx, instride, nch, scale);
}

__global__ __launch_bounds__(256) void conv_silu_bf(
    const float* __restrict__ xin, const float* __restrict__ w,
    unsigned short* __restrict__ out16, int instride, int nch, float scale) {
  int idx = blockIdx.x * 256 + threadIdx.x;
  out16[idx] = f2bf(conv_core(xin, w, idx, instride, nch, scale));
}

__global__ __launch_bounds__(256) void conv_silu_fb(
    const float* __restrict__ xin, const float* __restrict__ w,
    float* __restrict__ outp, unsigned short* __restrict__ out16,
    int instride, int nch, float scale) {
  int idx = blockIdx.x * 256 + threadIdx.x;
  float v = conv_core(xin, w, idx, instride, nch, scale);
  outp[idx] = v;
  out16[idx] = f2bf(v);
}

// ---------------------------------------------------------------------------
// v[c][e] f32 -> vT[e][c] bf16 per (n,hk).  grid = 128 blocks (b = n*8+hk).
// ---------------------------------------------------------------------------
__global__ __launch_bounds__(256) void vtr_kernel(
    const float* __restrict__ vs, unsigned short* __restrict__ vT16) {
  int b = blockIdx.x;
  __shared__ float t[64 * 132];
  int tid = threadIdx.x;
  size_t gbase = ((size_t)(b >> 3)) * 65536 + ((size_t)(b & 7)) * 128;
#pragma unroll
  for (int g = 0; g < 8; ++g) {
    int i = tid + g * 256;              // 2048 float4 total
    int c = i >> 5, e4 = i & 31;
    float4 v = *(const float4*)(vs + gbase + (size_t)c * 1024 + e4 * 4);
    t[c * 132 + e4 * 4 + 0] = v.x;
    t[c * 132 + e4 * 4 + 1] = v.y;
    t[c * 132 + e4 * 4 + 2] = v.z;
    t[c * 132 + e4 * 4 + 3] = v.w;
  }
  __syncthreads();
  int e = tid >> 1, half = tid & 1;
  size_t obase = ((size_t)b << 13) + (size_t)e * 64 + half * 32;
#pragma unroll
  for (int cc = 0; cc < 8; ++cc) {
    int c0 = half * 32 + cc * 4;
    ushort4 u;
    u.x = f2bf(t[(c0 + 0) * 132 + e]);
    u.y = f2bf(t[(c0 + 1) * 132 + e]);
    u.z = f2bf(t[(c0 + 2) * 132 + e]);
    u.w = f2bf(t[(c0 + 3) * 132 + e]);
    *(ushort4*)(vT16 + obase + cc * 4) = u;
  }
}

// ---------------------------------------------------------------------------
// Fused skinny projections + gate nonlinearities.  One block per timestep.
// ---------------------------------------------------------------------------
__global__ __launch_bounds__(256) void gates_fused(
    const float* __restrict__ x, const float* __restrict__ Wa,
    const float* __restrict__ Wb, const float* __restrict__ Wal,
    const float* __restrict__ A_log, const float* __restrict__ dtb,
    const float* __restrict__ bbv, const float* __restrict__ balv,
    float* __restrict__ glog, float* __restrict__ beta,
    float* __restrict__ alpha) {
  int t = blockIdx.x;
  __shared__ float xr[2048];
  __shared__ float part[256];
  int tid = threadIdx.x;
  for (int i = tid; i < 512; i += 256)
    ((float4*)xr)[i] = ((const float4*)(x + (size_t)t * 2048))[i];
  __syncthreads();
  int o = tid >> 2, p = tid & 3;
  float s = 0.f;
  if (o < 48) {
    const float* W = (o < 16) ? Wa : (o < 32) ? Wb : Wal;
    int h = o & 15;
    int k0 = p * 512;
    for (int k = k0; k < k0 + 512; ++k) s = fmaf(xr[k], W[k * 16 + h], s);
  }
  part[tid] = s;
  __syncthreads();
  if (o < 48 && p == 0) {
    float dot = part[tid] + part[tid + 1] + part[tid + 2] + part[tid + 3];
    int h = o & 15;
    if (o < 16) {
      float za = dot + dtb[h];
      float sp = fmaxf(za, 0.f) + log1pf(expf(-fabsf(za)));
      glog[t * 16 + h] = -expf(A_log[h]) * sp;
    } else if (o < 32) {
      beta[t * 16 + h] = 1.f / (1.f + expf(-(dot + bbv[h])));
    } else {
      alpha[t * 16 + h] = 1.f / (1.f + expf(-(dot + balv[h])));
    }
  }
}

// ---------------------------------------------------------------------------
// Per-(h,n) inclusive cumsum of glog within chunk + w_end = exp(G-cs)*beta.
// ---------------------------------------------------------------------------
__global__ __launch_bounds__(256) void cumsum_kernel(
    const float* __restrict__ glog, const float* __restrict__ beta,
    float* __restrict__ cs, float* __restrict__ wend) {
  int idx = threadIdx.x;            // h*16+n
  int n = idx & 15;
  float acc = 0.f;
  for (int c = 0; c < CSZ; ++c) {
    acc += glog[(n * CSZ + c) * NHQ + (idx >> 4)];
    cs[idx * CSZ + c] = acc;
  }
  float G = acc;
  for (int c = 0; c < CSZ; ++c) {
    wend[idx * CSZ + c] =
        expf(G - cs[idx * CSZ + c]) * beta[(n * CSZ + c) * NHQ + (idx >> 4)];
  }
}

// ---------------------------------------------------------------------------
// Gram increments per (h,n): dH = sum_c w*k*k^T (exactly symmetric), dB = w*k*v^T
// ---------------------------------------------------------------------------
__global__ __launch_bounds__(256) void dhb_kernel(
    const float* __restrict__ ks, const float* __restrict__ vs,
    const float* __restrict__ wend, float* __restrict__ dH,
    float* __restrict__ dB) {
  int bid = blockIdx.x;             // h*16+n
  int h = bid >> 4, n = bid & 15;
  int hk = h >> 1;
  __shared__ float kt[CSZ][HDIM];
  __shared__ float vt[CSZ][HDIM];
  int tid = threadIdx.x;
  for (int l = tid; l < CSZ * HDIM; l += 256) {
    int c = l >> 7, d = l & 127;
    size_t g = (size_t)(n * CSZ + c) * (NHK * HDIM) + hk * HDIM + d;
    kt[c][d] = ks[g];
    vt[c][d] = vs[g];
  }
  __syncthreads();
  int r = tid >> 1;
  int e0 = (tid & 1) << 6;
  float accH[64], accB[64];
#pragma unroll
  for (int j = 0; j < 64; j++) { accH[j] = 0.f; accB[j] = 0.f; }
  for (int c = 0; c < CSZ; ++c) {
    float w = wend[bid * CSZ + c];
    float kr = kt[c][r];
    float a = w * kr;
    const float4* kr4 = (const float4*)(&kt[c][e0]);
    const float4* vr4 = (const float4*)(&vt[c][e0]);
#pragma unroll
    for (int j4 = 0; j4 < 16; ++j4) {
      float4 kv = kr4[j4];
      float4 vv = vr4[j4];
      accH[j4*4+0] = fmaf(w, kr * kv.x, accH[j4*4+0]);
      accH[j4*4+1] = fmaf(w, kr * kv.y, accH[j4*4+1]);
      accH[j4*4+2] = fmaf(w, kr * kv.z, accH[j4*4+2]);
      accH[j4*4+3] = fmaf(w, kr * kv.w, accH[j4*4+3]);
      accB[j4*4+0] = fmaf(a, vv.x, accB[j4*4+0]);
      accB[j4*4+1] = fmaf(a, vv.y, accB[j4*4+1]);
      accB[j4*4+2] = fmaf(a, vv.z, accB[j4*4+2]);
      accB[j4*4+3] = fmaf(a, vv.w, accB[j4*4+3]);
    }
  }
  size_t base = ((size_t)bid * HDIM + r) * HDIM + e0;
#pragma unroll
  for (int j = 0; j < 64; j++) { dH[base + j] = accH[j]; dB[base + j] = accB[j]; }
}

// ---------------------------------------------------------------------------
// Inter-chunk scan (in-place): store state at chunk start; A gets +ridge diag.
// ---------------------------------------------------------------------------
__global__ __launch_bounds__(256) void scan_kernel(
    float* __restrict__ dH, float* __restrict__ dB,
    const float* __restrict__ cs) {
  int idx = blockIdx.x * 256 + threadIdx.x;  // h*16384 + de
  int h = idx >> 14, de = idx & 16383;
  float Hs = 0.f, Bs = 0.f;
  bool diag = ((de % 129) == 0);
#pragma unroll 1
  for (int n = 0; n < NCH; ++n) {
    size_t off = ((size_t)(h * 16 + n) << 14) + de;
    float dh = dH[off], db = dB[off];
    dH[off] = diag ? (Hs + 0.02f) : Hs;
    dB[off] = Bs;
    float g = expf(cs[(h * 16 + n) * CSZ + (CSZ - 1)]);
    Hs = fmaf(g, Hs, dh);
    Bs = fmaf(g, Bs, db);
  }
}

// ---------------------------------------------------------------------------
// In-place A (f32) -> split bf16 MFMA A-operand fragments + trace.
// ---------------------------------------------------------------------------
__global__ __launch_bounds__(256) void afrag_kernel(
    float* __restrict__ Aall, float* __restrict__ traces) {
  int bid = blockIdx.x;
  float* Ag = Aall + ((size_t)bid << 14);
  __shared__ float As[16384];
  int tid = threadIdx.x;
  for (int i = tid; i < 4096; i += 256)
    ((float4*)As)[i] = ((const float4*)Ag)[i];
  __syncthreads();
  if (tid < 64) {
    float tv = As[tid * 129] + As[(tid + 64) * 129];
#pragma unroll
    for (int off = 32; off; off >>= 1) tv += __shfl_down(tv, off);
    if (tid == 0) traces[bid] = tv;
  }
  unsigned short* Ah = (unsigned short*)Ag;
  unsigned short* Al = Ah + 16384;
#pragma unroll
  for (int c8 = 0; c8 < 8; ++c8) {
    int s0 = tid * 64 + c8 * 8;
    int frag = s0 >> 9, mlane = (s0 >> 3) & 63;
    int m = ((frag >> 2) << 4) + (mlane & 15);
    int k = ((frag & 3) << 5) + ((mlane >> 4) << 3);
    unsigned short hi[8], lo[8];
#pragma unroll
    for (int j = 0; j < 8; ++j) {
      float a = As[m * 128 + k + j];
      unsigned short h = f2bf(a);
      hi[j] = h;
      lo[j] = f2bf(a - bf2f(h));
    }
    *(uint4*)(Ah + s0) = *(uint4*)hi;
    *(uint4*)(Al + s0) = *(uint4*)lo;
  }
}

// ---------------------------------------------------------------------------
// Chebyshev solve via MFMA.  One block (512 thr, 8 waves) per (h,n) matrix.
// A in registers (split-bf16); dvec single-bf16 double-buffered LDS (64 KB).
// Emits X directly as hi/lo bf16 B-operand fragments (in place over B0).
// ---------------------------------------------------------------------------
__global__ __launch_bounds__(512) void cheb_kernel(
    const unsigned short* __restrict__ Afrag, const float* __restrict__ traces,
    float* __restrict__ Ball) {
  int bid = blockIdx.x;
  const unsigned short* __restrict__ Ah = Afrag + ((size_t)bid << 15);
  float* __restrict__ Bg = Ball + ((size_t)bid << 14);
  __shared__ unsigned short dT[2][16384];
  int tid = threadIdx.x;
  int w = tid >> 6, lane = tid & 63;
  int ln = lane & 15, q = lane >> 4;

  float lmax = traces[bid];
  const float lmin = 0.02f;
  float theta = 0.5f * (lmax + lmin);
  float delta = 0.5f * (lmax - lmin);
  float sigma1 = theta / delta;
  float rho = delta / theta;
  float invtheta = 1.f / theta;

  short8 afr[4][2];
#pragma unroll
  for (int kt = 0; kt < 4; ++kt) {
    afr[kt][0] = *(const short8*)(Ah + (((w * 4 + kt) * 64 + lane) << 3));
    afr[kt][1] = *(const short8*)(Ah + 16384 + (((w * 4 + kt) * 64 + lane) << 3));
  }

  int cw = (w << 1) + (q >> 1);
  int j0 = (q & 1) << 2;

  float xx[8][4], rr[8][4], dd[8][4];
#pragma unroll
  for (int nt = 0; nt < 8; ++nt) {
    int n = nt * 16 + ln;
    ushort4 pack;
    unsigned short* pp = (unsigned short*)&pack;
#pragma unroll
    for (int rg = 0; rg < 4; ++rg) {
      float b = Bg[(w * 16 + q * 4 + rg) * 128 + n];
      rr[nt][rg] = b;
      xx[nt][rg] = 0.f;
      unsigned short dq = f2bf(b * invtheta);
      dd[nt][rg] = bf2f(dq);
      pp[rg] = dq;
    }
    *(ushort4*)(&dT[0][n * 128 + ((cw ^ ln) << 3) + j0]) = pack;
  }
  __syncthreads();

#pragma unroll 1
  for (int it = 0; it < 30; ++it) {
    const unsigned short* dTr = dT[it & 1];
    unsigned short* dTw = dT[(it & 1) ^ 1];
    floatx4 acc[8];
#pragma unroll
    for (int nt = 0; nt < 8; ++nt) acc[nt] = (floatx4)(0.f);
#pragma unroll
    for (int kt = 0; kt < 4; ++kt) {
      short8 df[8];
#pragma unroll
      for (int nt = 0; nt < 8; ++nt)
        df[nt] = *(const short8*)(dTr + (nt * 16 + ln) * 128 +
                                  (((kt * 4 + q) ^ ln) << 3));
#pragma unroll
      for (int nt = 0; nt < 8; ++nt) {
        acc[nt] = __builtin_amdgcn_mfma_f32_16x16x32_bf16(
            afr[kt][0], df[nt], acc[nt], 0, 0, 0);
        acc[nt] = __builtin_amdgcn_mfma_f32_16x16x32_bf16(
            afr[kt][1], df[nt], acc[nt], 0, 0, 0);
      }
    }
    float rho_n = 1.f / (2.f * sigma1 - rho);
    float c1s = rho_n * rho;
    float c2s = 2.f * rho_n / delta;
#pragma unroll
    for (int nt = 0; nt < 8; ++nt) {
      int n = nt * 16 + ln;
      ushort4 pack;
      unsigned short* pp = (unsigned short*)&pack;
#pragma unroll
      for (int rg = 0; rg < 4; ++rg) {
        xx[nt][rg] += dd[nt][rg];
        rr[nt][rg] -= acc[nt][rg];
        float dn = fmaf(c1s, dd[nt][rg], c2s * rr[nt][rg]);
        unsigned short dq = f2bf(dn);
        dd[nt][rg] = bf2f(dq);
        pp[rg] = dq;
      }
      *(ushort4*)(&dTw[n * 128 + ((cw ^ ln) << 3) + j0]) = pack;
    }
    rho = rho_n;
    __syncthreads();
  }

  // X -> hi/lo bf16 B-operand fragments, in place over B0.
  unsigned short* Xf = (unsigned short*)Bg;
  int dt = w >> 1;
  int hi2 = ((w & 1) << 1) + (q >> 1);
#pragma unroll
  for (int nt = 0; nt < 8; ++nt) {
    ushort4 h4, l4;
    unsigned short* hp = (unsigned short*)&h4;
    unsigned short* lp = (unsigned short*)&l4;
#pragma unroll
    for (int rg = 0; rg < 4; ++rg) {
      float xv = xx[nt][rg];
      unsigned short h = f2bf(xv);
      hp[rg] = h;
      lp[rg] = f2bf(xv - bf2f(h));
    }
    size_t off = (size_t)(nt * 4 + dt) * 512 + (hi2 * 16 + ln) * 8 + j0;
    *(ushort4*)(Xf + off) = h4;
    *(ushort4*)(Xf + 16384 + off) = l4;
  }
}

// ---------------------------------------------------------------------------
// Attention per (h,n), all-MFMA:
//   O = exp(cs)*(q@X) + tril(exp(cs_c-cs_j)*beta_j * q@k^T) @ v + alpha*v.
// q/k staged bf16 in LDS (pitch 136 = 128+8!); X streamed as hi/lo B-frags;
// S bounced through LDS wave-locally; v^T streamed as B-frags.
// ---------------------------------------------------------------------------
__global__ __launch_bounds__(256) void attn_kernel(
    const unsigned short* __restrict__ q16, const unsigned short* __restrict__ k16,
    const unsigned short* __restrict__ vT16, const unsigned short* __restrict__ Xf,
    const float* __restrict__ vs, const float* __restrict__ cs,
    const float* __restrict__ beta, const float* __restrict__ alpha,
    float* __restrict__ o) {
  int bid = blockIdx.x;             // h*16+n
  int h = bid >> 4, n = bid & 15;
  int hk = h >> 1;
  __shared__ unsigned short qb[64 * 136];   // rows are 128 bf16 + 8 pad
  __shared__ unsigned short kb[64 * 136];
  __shared__ unsigned short Sb[64 * 72];
  __shared__ float csL[64], ecsL[64], betaL[64], alphaL[64];
  int tid = threadIdx.x;
  int w = tid >> 6, lane = tid & 63;
  int ln = lane & 15, hi = lane >> 4;

  {
    size_t qgb = (((size_t)(n * 64)) * 16 + h) * 128;
    size_t kgb = (((size_t)(n * 64)) * 8 + hk) * 128;
#pragma unroll
    for (int g = 0; g < 4; ++g) {
      int i = tid + g * 256;
      int c = i >> 4, ch = i & 15;
      *(uint4*)(qb + c * 136 + ch * 8) =
          *(const uint4*)(q16 + qgb + (size_t)c * 2048 + ch * 8);
      *(uint4*)(kb + c * 136 + ch * 8) =
          *(const uint4*)(k16 + kgb + (size_t)c * 1024 + ch * 8);
    }
    if (tid < 64) {
      float cv = cs[bid * 64 + tid];
      csL[tid] = cv;
      ecsL[tid] = expf(cv);
      betaL[tid] = beta[(n * 64 + tid) * 16 + h];
      alphaL[tid] = alpha[(n * 64 + tid) * 16 + h];
    }
  }
  __syncthreads();

  // q A-frags (k-dim = d), reused in phases 1 and 2
  short8 aq[4];
#pragma unroll
  for (int dt = 0; dt < 4; ++dt)
    aq[dt] = *(const short8*)(qb + (w * 16 + ln) * 136 + dt * 32 + hi * 8);

  // phase 1: o_inter = q @ X (hi+lo planes), then scale rows by exp(cs)
  const unsigned short* Xb = Xf + ((size_t)bid << 15);
  floatx4 acc[8];
#pragma unroll
  for (int et = 0; et < 8; ++et) {
    floatx4 a = (floatx4)(0.f);
#pragma unroll
    for (int dt = 0; dt < 4; ++dt) {
      short8 xh = *(const short8*)(Xb + (et * 4 + dt) * 512 + lane * 8);
      short8 xl = *(const short8*)(Xb + 16384 + (et * 4 + dt) * 512 + lane * 8);
      a = __builtin_amdgcn_mfma_f32_16x16x32_bf16(aq[dt], xh, a, 0, 0, 0);
      a = __builtin_amdgcn_mfma_f32_16x16x32_bf16(aq[dt], xl, a, 0, 0, 0);
    }
    acc[et] = a;
  }
#pragma unroll
  for (int et = 0; et < 8; ++et)
#pragma unroll
    for (int rg = 0; rg < 4; ++rg)
      acc[et][rg] *= ecsL[w * 16 + hi * 4 + rg];

  // phase 2: gated causal scores -> Sb (bf16), wave-local rows
#pragma unroll
  for (int jt = 0; jt < 4; ++jt) {
    if (jt <= w) {
      floatx4 s = (floatx4)(0.f);
#pragma unroll
      for (int dt = 0; dt < 4; ++dt) {
        short8 bk = *(const short8*)(kb + (jt * 16 + ln) * 136 + dt * 32 + hi * 8);
        s = __builtin_amdgcn_mfma_f32_16x16x32_bf16(aq[dt], bk, s, 0, 0, 0);
      }
      int j = jt * 16 + ln;
      float csj = csL[j], bj = betaL[j];
#pragma unroll
      for (int rg = 0; rg < 4; ++rg) {
        int c = w * 16 + hi * 4 + rg;
        float v = (j <= c) ? s[rg] * expf(csL[c] - csj) * bj : 0.f;
        Sb[c * 72 + j] = f2bf(v);
      }
    } else {
#pragma unroll
      for (int rg = 0; rg < 4; ++rg)
        Sb[(w * 16 + hi * 4 + rg) * 72 + jt * 16 + ln] = 0;
    }
  }

  // phase 3: O += S @ v  (S A-frags wave-local; v^T B-frags from global)
  const unsigned short* vTb = vT16 + ((size_t)(n * 8 + hk) << 13);
#pragma unroll
  for (int et = 0; et < 8; ++et) {
#pragma unroll
    for (int kt = 0; kt < 2; ++kt) {
      short8 as = *(const short8*)(Sb + (w * 16 + ln) * 72 + kt * 32 + hi * 8);
      short8 bv = *(const short8*)(vTb + (et * 16 + ln) * 64 + kt * 32 + hi * 8);
      acc[et] = __builtin_amdgcn_mfma_f32_16x16x32_bf16(as, bv, acc[et], 0, 0, 0);
    }
  }

  // epilogue: + alpha*v, store
#pragma unroll
  for (int et = 0; et < 8; ++et) {
#pragma unroll
    for (int rg = 0; rg < 4; ++rg) {
      int c = w * 16 + hi * 4 + rg, e = et * 16 + ln;
      size_t oaddr = (((size_t)(n * 64 + c)) * 16 + h) * 128 + e;
      size_t vaddr = (((size_t)(n * 64 + c)) * 8 + hk) * 128 + e;
      o[oaddr] = acc[et][rg] + alphaL[c] * vs[vaddr];
    }
  }
}

// ---------------------------------------------------------------------------
// Gated RMSNorm -> bf16 output.  g read from xall (cols 4096.., stride 6144).
// ---------------------------------------------------------------------------
__global__ __launch_bounds__(256) void rmsnorm_kernel(
    const float* __restrict__ o, const float* __restrict__ xall,
    const float* __restrict__ norm_w, unsigned short* __restrict__ onorm) {
  int wave = threadIdx.x >> 6, lane = threadIdx.x & 63;
  int row = blockIdx.x * 4 + wave;          // t*16 + h
  size_t base = (size_t)row * HDIM;
  size_t gbase = (size_t)(row >> 4) * 6144 + 4096 + (size_t)(row & 15) * HDIM;
  float v0 = o[base + lane], v1 = o[base + lane + 64];
  float ss = fmaf(v0, v0, v1 * v1);
#pragma unroll
  for (int off = 32; off; off >>= 1) ss += __shfl_down(ss, off);
  ss = __shfl(ss, 0);
  float rinv = rsqrtf(ss * (1.f / 128.f) + 1e-6f);
  float g0 = xall[gbase + lane], g1 = xall[gbase + lane + 64];
  float s0 = g0 / (1.f + expf(-g0));
  float s1 = g1 / (1.f + expf(-g1));
  onorm[base + lane]      = f2bf(v0 * rinv * norm_w[lane] * s0);
  onorm[base + lane + 64] = f2bf(v1 * rinv * norm_w[lane + 64] * s1);
}

// ---------------------------------------------------------------------------
extern "C" void kernel_launch(void* const* d_in, const int* in_sizes, int n_in,
                              void* d_out, int out_size, void* d_ws,
                              size_t ws_size, hipStream_t stream) {
  (void)in_sizes; (void)n_in; (void)out_size; (void)ws_size;
  const float* x      = (const float*)d_in[0];
  const float* Wq     = (const float*)d_in[1];
  const float* Wk     = (const float*)d_in[2];
  const float* Wv     = (const float*)d_in[3];
  const float* convq  = (const float*)d_in[4];
  const float* convk  = (const float*)d_in[5];
  const float* convv  = (const float*)d_in[6];
  const float* Wa     = (const float*)d_in[7];
  const float* A_log  = (const float*)d_in[8];
  const float* dtb    = (const float*)d_in[9];
  const float* Wb     = (const float*)d_in[10];
  const float* bbv    = (const float*)d_in[11];
  const float* Wal    = (const float*)d_in[12];
  const float* balv   = (const float*)d_in[13];
  const float* Wg     = (const float*)d_in[14];
  const float* norm_w = (const float*)d_in[15];
  const float* Wo     = (const float*)d_in[16];
  float* out = (float*)d_out;

  // workspace layout (float slots), ~88.5 MB total
  float* p = (float*)d_ws;
  float* xall  = p; p += 6291456;   // [L][6144]: q|k|v|g projections
  float* qslot = p; p += 2097152;   // carved: qs16 | ks16 | vT16 (bf16)
  float* ks2   = p; p += 1048576;   // + vs2 contiguous: reused as WtWo (bf16)
  float* vs2   = p; p += 1048576;
  float* ob    = p; p += 2097152;
  float* glog  = p; p += 16384;
  float* beta  = p; p += 16384;
  float* alpha = p; p += 16384;
  float* csb   = p; p += 16384;
  float* wend  = p; p += 16384;
  float* traces= p; p += 16384;     // 256 used
  float* dHn   = p; p += 4194304;   // -> A -> A-frags (bf16 hi/lo) in place
  float* dBn   = p; p += 4194304;   // -> B0 -> X-frags (bf16 hi/lo) in place
  unsigned short* xb16 = (unsigned short*)p; p += 1048576;

  unsigned short* qs16 = (unsigned short*)qslot;     // 1024*2048
  unsigned short* ks16 = qs16 + 2097152;             // 1024*1024
  unsigned short* vT16 = ks16 + 1048576;             // 128*128*64
  unsigned short* WtAll = (unsigned short*)dHn;      // 24 MB over dHn+dBn
  unsigned short* WtWo  = (unsigned short*)ks2;      // 8 MB over ks2+vs2
  unsigned short* onorm16 = xb16;                    // free after projections

  dim3 blk(256);
  castbf<<<2048, blk, 0, stream>>>(x, xb16);
  // batched projection: Wt rows: q 0-2047, k 2048-3071, v 3072-4095, g 4096-6143
  tcast<<<dim3(64, 64), blk, 0, stream>>>(Wq, WtAll, 2048, 2048);
  tcast<<<dim3(32, 64), blk, 0, stream>>>(Wk, WtAll + (size_t)2048 * 2048, 2048, 1024);
  tcast<<<dim3(32, 64), blk, 0, stream>>>(Wv, WtAll + (size_t)3072 * 2048, 2048, 1024);
  tcast<<<dim3(64, 64), blk, 0, stream>>>(Wg, WtAll + (size_t)4096 * 2048, 2048, 2048);
  gemm_bf16<<<dim3(96, 8), blk, 0, stream>>>(xb16, WtAll, xall, 1024, 6144, 2048);
  // causal conv + silu (q scaled by HD^-0.5; q bf16-only, k f32+bf16, v f32)
  conv_silu_bf<<<8192, blk, 0, stream>>>(xall, convq, qs16, 6144, 2048,
                                         0.08838834764831845f);
  conv_silu_fb<<<4096, blk, 0, stream>>>(xall + 2048, convk, ks2, ks16, 6144,
                                         1024, 1.0f);
  conv_silu<<<4096, blk, 0, stream>>>(xall + 3072, convv, vs2, 6144, 1024, 1.0f);
  vtr_kernel<<<128, blk, 0, stream>>>(vs2, vT16);
  // gates + cumulative decay
  gates_fused<<<1024, blk, 0, stream>>>(x, Wa, Wb, Wal, A_log, dtb, bbv, balv,
                                        glog, beta, alpha);
  cumsum_kernel<<<1, blk, 0, stream>>>(glog, beta, csb, wend);
  // gram increments (overwrites WtAll region), scan, A-frag prep, Chebyshev
  dhb_kernel<<<256, blk, 0, stream>>>(ks2, vs2, wend, dHn, dBn);
  scan_kernel<<<1024, blk, 0, stream>>>(dHn, dBn, csb);
  afrag_kernel<<<256, blk, 0, stream>>>(dHn, traces);
  cheb_kernel<<<256, dim3(512), 0, stream>>>((unsigned short*)dHn, traces, dBn);
  // attention (all-MFMA)
  attn_kernel<<<256, blk, 0, stream>>>(qs16, ks16, vT16, (unsigned short*)dBn,
                                       vs2, csb, beta, alpha, ob);
  // gated RMSNorm (bf16 out) + output projection (WtWo overwrites ks2/vs2)
  rmsnorm_kernel<<<4096, blk, 0, stream>>>(ob, xall, norm_w, onorm16);
  tcast<<<dim3(64, 64), blk, 0, stream>>>(Wo, WtWo, 2048, 2048);
  gemm_bf16<<<dim3(32, 8), blk, 0, stream>>>(onorm16, WtWo, out, 1024, 2048, 2048);
}

// Round 8
// 440.386 us; speedup vs baseline: 10.2970x; 1.1646x over previous
//
#include <hip/hip_runtime.h>
#include <math.h>

// GatedKalmaNet: B=1, L=1024, D=2048, HQ=16, HK=8, HD=128, CONV=4, CHUNK=64,
// Nc=16, NUM_ITER=30, RIDGE=0.02, EPS=1e-6.

#define LSEQ 1024
#define DM   2048
#define NHQ  16
#define NHK  8
#define HDIM 128
#define NCH  16
#define CSZ  64

typedef __attribute__((ext_vector_type(8))) short short8;
typedef __attribute__((ext_vector_type(4))) float floatx4;

// f32 -> bf16 RNE
__device__ __forceinline__ unsigned short f2bf(float f) {
  unsigned int u = __float_as_uint(f);
  u += 0x7fffu + ((u >> 16) & 1u);
  return (unsigned short)(u >> 16);
}
__device__ __forceinline__ float bf2f(unsigned short u) {
  return __uint_as_float(((unsigned int)u) << 16);
}

// ---------------------------------------------------------------------------
// Transpose-cast body: W[K][N] f32 -> Wt[N][K] bf16, one 32x32 tile.
// ---------------------------------------------------------------------------
__device__ __forceinline__ void tcast_body(
    const float* __restrict__ W, unsigned short* __restrict__ Wt,
    int K, int N, int bn, int bk, int tid, float* __restrict__ t) {
  int r = tid >> 5, c = tid & 31;
#pragma unroll
  for (int i = 0; i < 4; ++i)
    t[(r + i * 8) * 33 + c] = W[(size_t)(bk * 32 + r + i * 8) * N + bn * 32 + c];
  __syncthreads();
#pragma unroll
  for (int i = 0; i < 4; ++i)
    Wt[(size_t)(bn * 32 + r + i * 8) * K + bk * 32 + c] =
        f2bf(t[c * 33 + r + i * 8]);
}

// ---------------------------------------------------------------------------
// prep: castbf(x) + tcast(Wq,Wk,Wv,Wg) in one launch.  14336 blocks.
// ---------------------------------------------------------------------------
__global__ __launch_bounds__(256) void prep_kernel(
    const float* __restrict__ x, const float* __restrict__ Wq,
    const float* __restrict__ Wk, const float* __restrict__ Wv,
    const float* __restrict__ Wg, unsigned short* __restrict__ xb16,
    unsigned short* __restrict__ WtAll) {
  __shared__ float t[32 * 33];
  int b = blockIdx.x, tid = threadIdx.x;
  if (b < 2048) {
    int i = b * 256 + tid;
    float4 v = ((const float4*)x)[i];
    ushort4 u;
    u.x = f2bf(v.x); u.y = f2bf(v.y); u.z = f2bf(v.z); u.w = f2bf(v.w);
    ((ushort4*)xb16)[i] = u;
  } else if (b < 6144) {
    int r = b - 2048;
    tcast_body(Wq, WtAll, 2048, 2048, r & 63, r >> 6, tid, t);
  } else if (b < 8192) {
    int r = b - 6144;
    tcast_body(Wk, WtAll + (size_t)2048 * 2048, 2048, 1024, r & 31, r >> 5, tid, t);
  } else if (b < 10240) {
    int r = b - 8192;
    tcast_body(Wv, WtAll + (size_t)3072 * 2048, 2048, 1024, r & 31, r >> 5, tid, t);
  } else {
    int r = b - 10240;
    tcast_body(Wg, WtAll + (size_t)4096 * 2048, 2048, 2048, r & 63, r >> 6, tid, t);
  }
}

// ---------------------------------------------------------------------------
// bf16 MFMA GEMM: C[M,N](f32) = A[M,K](bf16) @ Bt[N,K](bf16)^T.
// BM=128 BN=64 BK=64; 256 thr = 4 waves (2x2); wave tile 64x32.
// ---------------------------------------------------------------------------
__global__ __launch_bounds__(256) void gemm_bf16(
    const unsigned short* __restrict__ A, const unsigned short* __restrict__ Bt,
    float* __restrict__ C, int M, int N, int K) {
  __shared__ unsigned short As[128 * 72];
  __shared__ unsigned short Bs[64 * 72];
  int tid = threadIdx.x;
  int wave = tid >> 6, lane = tid & 63;
  int ln = lane & 15, hi = lane >> 4;
  int wm = wave & 1, wn = wave >> 1;
  int m0 = blockIdx.y * 128, n0 = blockIdx.x * 64;

  floatx4 acc[4][2];
#pragma unroll
  for (int mt = 0; mt < 4; ++mt)
#pragma unroll
    for (int nt = 0; nt < 2; ++nt) acc[mt][nt] = (floatx4)(0.f);

  for (int k0 = 0; k0 < K; k0 += 64) {
#pragma unroll
    for (int g = 0; g < 4; ++g) {
      int l = tid + g * 256;
      int m = l >> 3, go = l & 7;
      uint4 v = *(const uint4*)(A + (size_t)(m0 + m) * K + k0 + go * 8);
      *(uint4*)(As + m * 72 + go * 8) = v;
    }
#pragma unroll
    for (int g = 0; g < 2; ++g) {
      int l = tid + g * 256;
      int n = l >> 3, go = l & 7;
      uint4 v = *(const uint4*)(Bt + (size_t)(n0 + n) * K + k0 + go * 8);
      *(uint4*)(Bs + n * 72 + go * 8) = v;
    }
    __syncthreads();
#pragma unroll
    for (int kb = 0; kb < 2; ++kb) {
      short8 a[4], b[2];
#pragma unroll
      for (int mt = 0; mt < 4; ++mt)
        a[mt] = *(const short8*)(As + (wm * 64 + mt * 16 + ln) * 72 + kb * 32 + hi * 8);
#pragma unroll
      for (int nt = 0; nt < 2; ++nt)
        b[nt] = *(const short8*)(Bs + (wn * 32 + nt * 16 + ln) * 72 + kb * 32 + hi * 8);
#pragma unroll
      for (int mt = 0; mt < 4; ++mt)
#pragma unroll
        for (int nt = 0; nt < 2; ++nt)
          acc[mt][nt] = __builtin_amdgcn_mfma_f32_16x16x32_bf16(
              a[mt], b[nt], acc[mt][nt], 0, 0, 0);
    }
    __syncthreads();
  }
#pragma unroll
  for (int mt = 0; mt < 4; ++mt)
#pragma unroll
    for (int nt = 0; nt < 2; ++nt) {
      int col = n0 + wn * 32 + nt * 16 + ln;
      int rowb = m0 + wm * 64 + mt * 16 + hi * 4;
#pragma unroll
      for (int r = 0; r < 4; ++r)
        C[(size_t)(rowb + r) * N + col] = acc[mt][nt][r];
    }
}

// ---------------------------------------------------------------------------
// Causal depthwise conv (K=4) + silu core.
// ---------------------------------------------------------------------------
__device__ __forceinline__ float conv_core(
    const float* __restrict__ xin, const float* __restrict__ w,
    int idx, int instride, int nch, float scale) {
  int t = idx / nch, ch = idx - t * nch;
  float acc = 0.f;
#pragma unroll
  for (int j = 0; j < 4; ++j) {
    int tt = t + j - 3;
    float xv = (tt >= 0) ? xin[(size_t)tt * instride + ch] : 0.f;
    acc = fmaf(xv, w[ch * 4 + j], acc);
  }
  return acc / (1.f + expf(-acc)) * scale;
}

// ---------------------------------------------------------------------------
// conv_all: q (bf16 out), k (f32+bf16 out), v (f32 out).  16384 blocks.
// ---------------------------------------------------------------------------
__global__ __launch_bounds__(256) void conv_all(
    const float* __restrict__ xall, const float* __restrict__ convq,
    const float* __restrict__ convk, const float* __restrict__ convv,
    unsigned short* __restrict__ qs16, float* __restrict__ ks2,
    unsigned short* __restrict__ ks16, float* __restrict__ vs2) {
  int b = blockIdx.x, tid = threadIdx.x;
  if (b < 8192) {
    int idx = b * 256 + tid;
    qs16[idx] = f2bf(conv_core(xall, convq, idx, 6144, 2048,
                               0.08838834764831845f));
  } else if (b < 12288) {
    int idx = (b - 8192) * 256 + tid;
    float v = conv_core(xall + 2048, convk, idx, 6144, 1024, 1.0f);
    ks2[idx] = v;
    ks16[idx] = f2bf(v);
  } else {
    int idx = (b - 12288) * 256 + tid;
    vs2[idx] = conv_core(xall + 3072, convv, idx, 6144, 1024, 1.0f);
  }
}

// ---------------------------------------------------------------------------
// v[c][e] f32 -> vT[e][c] bf16 per (n,hk).  grid = 128 blocks (b = n*8+hk).
// ---------------------------------------------------------------------------
__global__ __launch_bounds__(256) void vtr_kernel(
    const float* __restrict__ vs, unsigned short* __restrict__ vT16) {
  int b = blockIdx.x;
  __shared__ float t[64 * 132];
  int tid = threadIdx.x;
  size_t gbase = ((size_t)(b >> 3)) * 65536 + ((size_t)(b & 7)) * 128;
#pragma unroll
  for (int g = 0; g < 8; ++g) {
    int i = tid + g * 256;
    int c = i >> 5, e4 = i & 31;
    float4 v = *(const float4*)(vs + gbase + (size_t)c * 1024 + e4 * 4);
    t[c * 132 + e4 * 4 + 0] = v.x;
    t[c * 132 + e4 * 4 + 1] = v.y;
    t[c * 132 + e4 * 4 + 2] = v.z;
    t[c * 132 + e4 * 4 + 3] = v.w;
  }
  __syncthreads();
  int e = tid >> 1, half = tid & 1;
  size_t obase = ((size_t)b << 13) + (size_t)e * 64 + half * 32;
#pragma unroll
  for (int cc = 0; cc < 8; ++cc) {
    int c0 = half * 32 + cc * 4;
    ushort4 u;
    u.x = f2bf(t[(c0 + 0) * 132 + e]);
    u.y = f2bf(t[(c0 + 1) * 132 + e]);
    u.z = f2bf(t[(c0 + 2) * 132 + e]);
    u.w = f2bf(t[(c0 + 3) * 132 + e]);
    *(ushort4*)(vT16 + obase + cc * 4) = u;
  }
}

// ---------------------------------------------------------------------------
// Fused skinny projections + gate nonlinearities.  One block per timestep.
// ---------------------------------------------------------------------------
__global__ __launch_bounds__(256) void gates_fused(
    const float* __restrict__ x, const float* __restrict__ Wa,
    const float* __restrict__ Wb, const float* __restrict__ Wal,
    const float* __restrict__ A_log, const float* __restrict__ dtb,
    const float* __restrict__ bbv, const float* __restrict__ balv,
    float* __restrict__ glog, float* __restrict__ beta,
    float* __restrict__ alpha) {
  int t = blockIdx.x;
  __shared__ float xr[2048];
  __shared__ float part[256];
  int tid = threadIdx.x;
  for (int i = tid; i < 512; i += 256)
    ((float4*)xr)[i] = ((const float4*)(x + (size_t)t * 2048))[i];
  __syncthreads();
  int o = tid >> 2, p = tid & 3;
  float s = 0.f;
  if (o < 48) {
    const float* W = (o < 16) ? Wa : (o < 32) ? Wb : Wal;
    int h = o & 15;
    int k0 = p * 512;
    for (int k = k0; k < k0 + 512; ++k) s = fmaf(xr[k], W[k * 16 + h], s);
  }
  part[tid] = s;
  __syncthreads();
  if (o < 48 && p == 0) {
    float dot = part[tid] + part[tid + 1] + part[tid + 2] + part[tid + 3];
    int h = o & 15;
    if (o < 16) {
      float za = dot + dtb[h];
      float sp = fmaxf(za, 0.f) + log1pf(expf(-fabsf(za)));
      glog[t * 16 + h] = -expf(A_log[h]) * sp;
    } else if (o < 32) {
      beta[t * 16 + h] = 1.f / (1.f + expf(-(dot + bbv[h])));
    } else {
      alpha[t * 16 + h] = 1.f / (1.f + expf(-(dot + balv[h])));
    }
  }
}

// ---------------------------------------------------------------------------
// Per-(h,n) inclusive cumsum of glog within chunk + w_end = exp(G-cs)*beta.
// ---------------------------------------------------------------------------
__global__ __launch_bounds__(256) void cumsum_kernel(
    const float* __restrict__ glog, const float* __restrict__ beta,
    float* __restrict__ cs, float* __restrict__ wend) {
  int idx = threadIdx.x;            // h*16+n
  int n = idx & 15;
  float acc = 0.f;
  for (int c = 0; c < CSZ; ++c) {
    acc += glog[(n * CSZ + c) * NHQ + (idx >> 4)];
    cs[idx * CSZ + c] = acc;
  }
  float G = acc;
  for (int c = 0; c < CSZ; ++c) {
    wend[idx * CSZ + c] =
        expf(G - cs[idx * CSZ + c]) * beta[(n * CSZ + c) * NHQ + (idx >> 4)];
  }
}

// ---------------------------------------------------------------------------
// Gram increments per (h,n) via MFMA:
//   dH = (s k)^T (s k), dB = (s k)^T (s v), s = sqrt(wend).
// sk, sv staged as hi/lo split-bf16 in MFMA fragment layout (64 KB LDS).
// K=64 -> 2 k-tiles.  Frag id = (idx/16)*2 + c/32; lane = ((c%32)/8)*16 +
// idx%16; elem j = c%8.  Same layout serves A- and B-operands.
// ---------------------------------------------------------------------------
__global__ __launch_bounds__(256) void dhb_kernel(
    const float* __restrict__ ks, const float* __restrict__ vs,
    const float* __restrict__ wend, float* __restrict__ dH,
    float* __restrict__ dB) {
  int bid = blockIdx.x;             // h*16+n
  int h = bid >> 4, n = bid & 15;
  int hk = h >> 1;
  __shared__ unsigned short skF[2][8192];   // hi/lo
  __shared__ unsigned short svF[2][8192];
  int tid = threadIdx.x;

  // stage: thread handles (e, c0..c0+7)
#pragma unroll
  for (int p = 0; p < 4; ++p) {
    int t2 = tid + p * 256;               // 0..1023
    int c0 = (t2 >> 7) << 3;              // 0,8,..,56
    int e = t2 & 127;
    int base = ((e >> 4) * 2 + (c0 >> 5)) * 512 +
               ((c0 & 31) >> 3) * 128 + (e & 15) * 8;
    unsigned short kh[8], kl[8], vh[8], vl[8];
#pragma unroll
    for (int j = 0; j < 8; ++j) {
      int c = c0 + j;
      float s = sqrtf(wend[bid * 64 + c]);
      size_t g = (size_t)(n * 64 + c) * 1024 + hk * 128 + e;
      float kf = s * ks[g];
      float vf = s * vs[g];
      unsigned short khh = f2bf(kf);
      kh[j] = khh; kl[j] = f2bf(kf - bf2f(khh));
      unsigned short vhh = f2bf(vf);
      vh[j] = vhh; vl[j] = f2bf(vf - bf2f(vhh));
    }
    *(uint4*)(&skF[0][base]) = *(uint4*)kh;
    *(uint4*)(&skF[1][base]) = *(uint4*)kl;
    *(uint4*)(&svF[0][base]) = *(uint4*)vh;
    *(uint4*)(&svF[1][base]) = *(uint4*)vl;
  }
  __syncthreads();

  int w = tid >> 6, lane = tid & 63;
  int ln = lane & 15, hi = lane >> 4;

  // A-frags for this wave's 2 m-tiles (rows d = (2w+mti)*16..), 2 k-tiles
  short8 ah[2][2], al[2][2];
#pragma unroll
  for (int mti = 0; mti < 2; ++mti) {
    int mt = w * 2 + mti;
#pragma unroll
    for (int ct = 0; ct < 2; ++ct) {
      ah[mti][ct] = *(const short8*)(&skF[0][((mt * 2 + ct) * 64 + lane) * 8]);
      al[mti][ct] = *(const short8*)(&skF[1][((mt * 2 + ct) * 64 + lane) * 8]);
    }
  }

  size_t gb = (size_t)bid << 14;
#pragma unroll
  for (int which = 0; which < 2; ++which) {
    const unsigned short (*BF)[8192] = which ? svF : skF;
    float* outp = which ? dB : dH;
#pragma unroll
    for (int nt = 0; nt < 8; ++nt) {
      floatx4 a0 = (floatx4)(0.f), a1 = (floatx4)(0.f);
#pragma unroll
      for (int ct = 0; ct < 2; ++ct) {
        short8 bh = *(const short8*)(&BF[0][((nt * 2 + ct) * 64 + lane) * 8]);
        short8 bl = *(const short8*)(&BF[1][((nt * 2 + ct) * 64 + lane) * 8]);
        a0 = __builtin_amdgcn_mfma_f32_16x16x32_bf16(ah[0][ct], bh, a0, 0, 0, 0);
        a0 = __builtin_amdgcn_mfma_f32_16x16x32_bf16(ah[0][ct], bl, a0, 0, 0, 0);
        a0 = __builtin_amdgcn_mfma_f32_16x16x32_bf16(al[0][ct], bh, a0, 0, 0, 0);
        a1 = __builtin_amdgcn_mfma_f32_16x16x32_bf16(ah[1][ct], bh, a1, 0, 0, 0);
        a1 = __builtin_amdgcn_mfma_f32_16x16x32_bf16(ah[1][ct], bl, a1, 0, 0, 0);
        a1 = __builtin_amdgcn_mfma_f32_16x16x32_bf16(al[1][ct], bh, a1, 0, 0, 0);
      }
      int e = nt * 16 + ln;
#pragma unroll
      for (int rg = 0; rg < 4; ++rg) {
        int d0 = (w * 2 + 0) * 16 + hi * 4 + rg;
        int d1 = (w * 2 + 1) * 16 + hi * 4 + rg;
        outp[gb + (size_t)d0 * 128 + e] = a0[rg];
        outp[gb + (size_t)d1 * 128 + e] = a1[rg];
      }
    }
  }
}

// ---------------------------------------------------------------------------
// Inter-chunk scan (in-place): store state at chunk start; A gets +ridge diag.
// ---------------------------------------------------------------------------
__global__ __launch_bounds__(256) void scan_kernel(
    float* __restrict__ dH, float* __restrict__ dB,
    const float* __restrict__ cs) {
  int idx = blockIdx.x * 256 + threadIdx.x;  // h*16384 + de
  int h = idx >> 14, de = idx & 16383;
  float Hs = 0.f, Bs = 0.f;
  bool diag = ((de % 129) == 0);
#pragma unroll 1
  for (int n = 0; n < NCH; ++n) {
    size_t off = ((size_t)(h * 16 + n) << 14) + de;
    float dh = dH[off], db = dB[off];
    dH[off] = diag ? (Hs + 0.02f) : Hs;
    dB[off] = Bs;
    float g = expf(cs[(h * 16 + n) * CSZ + (CSZ - 1)]);
    Hs = fmaf(g, Hs, dh);
    Bs = fmaf(g, Bs, db);
  }
}

// ---------------------------------------------------------------------------
// In-place A (f32) -> split bf16 MFMA A-operand fragments + trace.
// ---------------------------------------------------------------------------
__global__ __launch_bounds__(256) void afrag_kernel(
    float* __restrict__ Aall, float* __restrict__ traces) {
  int bid = blockIdx.x;
  float* Ag = Aall + ((size_t)bid << 14);
  __shared__ float As[16384];
  int tid = threadIdx.x;
  for (int i = tid; i < 4096; i += 256)
    ((float4*)As)[i] = ((const float4*)Ag)[i];
  __syncthreads();
  if (tid < 64) {
    float tv = As[tid * 129] + As[(tid + 64) * 129];
#pragma unroll
    for (int off = 32; off; off >>= 1) tv += __shfl_down(tv, off);
    if (tid == 0) traces[bid] = tv;
  }
  unsigned short* Ah = (unsigned short*)Ag;
  unsigned short* Al = Ah + 16384;
#pragma unroll
  for (int c8 = 0; c8 < 8; ++c8) {
    int s0 = tid * 64 + c8 * 8;
    int frag = s0 >> 9, mlane = (s0 >> 3) & 63;
    int m = ((frag >> 2) << 4) + (mlane & 15);
    int k = ((frag & 3) << 5) + ((mlane >> 4) << 3);
    unsigned short hi[8], lo[8];
#pragma unroll
    for (int j = 0; j < 8; ++j) {
      float a = As[m * 128 + k + j];
      unsigned short h = f2bf(a);
      hi[j] = h;
      lo[j] = f2bf(a - bf2f(h));
    }
    *(uint4*)(Ah + s0) = *(uint4*)hi;
    *(uint4*)(Al + s0) = *(uint4*)lo;
  }
}

// ---------------------------------------------------------------------------
// Chebyshev solve via MFMA.  One block (512 thr, 8 waves) per (h,n) matrix.
// A in registers (split-bf16); dvec single-bf16, double-buffered LDS stored
// in B-fragment-contiguous layout (lane-contiguous 1 KB blocks -> no LDS
// bank conflicts beyond structural).  X emitted as hi/lo B-frags in place.
// ---------------------------------------------------------------------------
__global__ __launch_bounds__(512) void cheb_kernel(
    const unsigned short* __restrict__ Afrag, const float* __restrict__ traces,
    float* __restrict__ Ball) {
  int bid = blockIdx.x;
  const unsigned short* __restrict__ Ah = Afrag + ((size_t)bid << 15);
  float* __restrict__ Bg = Ball + ((size_t)bid << 14);
  __shared__ unsigned short dT[2][16384];
  int tid = threadIdx.x;
  int w = tid >> 6, lane = tid & 63;
  int ln = lane & 15, q = lane >> 4;

  float lmax = traces[bid];
  const float lmin = 0.02f;
  float theta = 0.5f * (lmax + lmin);
  float delta = 0.5f * (lmax - lmin);
  float sigma1 = theta / delta;
  float rho = delta / theta;
  float invtheta = 1.f / theta;

  short8 afr[4][2];
#pragma unroll
  for (int kt = 0; kt < 4; ++kt) {
    afr[kt][0] = *(const short8*)(Ah + (((w * 4 + kt) * 64 + lane) << 3));
    afr[kt][1] = *(const short8*)(Ah + 16384 + (((w * 4 + kt) * 64 + lane) << 3));
  }

  // write slot for D[d = w*16+q*4+rg][n = nt*16+ln] in B-frag layout:
  // frag = nt*4 + (w>>1); lane2 = ((w&1)*2+(q>>1))*16 + ln; j = (q&1)*4+rg
  int wrA = ((w >> 1) * 64 + (((w & 1) * 2 + (q >> 1)) * 16 + ln)) * 8 +
            ((q & 1) << 2);

  float xx[8][4], rr[8][4], dd[8][4];
#pragma unroll
  for (int nt = 0; nt < 8; ++nt) {
    int nn = nt * 16 + ln;
    ushort4 pack;
    unsigned short* pp = (unsigned short*)&pack;
#pragma unroll
    for (int rg = 0; rg < 4; ++rg) {
      float b = Bg[(w * 16 + q * 4 + rg) * 128 + nn];
      rr[nt][rg] = b;
      xx[nt][rg] = 0.f;
      unsigned short dq = f2bf(b * invtheta);
      dd[nt][rg] = bf2f(dq);
      pp[rg] = dq;
    }
    *(ushort4*)(&dT[0][nt * 2048 + wrA]) = pack;
  }
  __syncthreads();

#pragma unroll 1
  for (int it = 0; it < 30; ++it) {
    const unsigned short* dTr = dT[it & 1];
    unsigned short* dTw = dT[(it & 1) ^ 1];
    floatx4 acc[8];
#pragma unroll
    for (int nt = 0; nt < 8; ++nt) acc[nt] = (floatx4)(0.f);
#pragma unroll
    for (int kt = 0; kt < 4; ++kt) {
      short8 df[8];
#pragma unroll
      for (int nt = 0; nt < 8; ++nt)
        df[nt] = *(const short8*)(dTr + (((nt * 4 + kt) * 64 + lane) << 3));
#pragma unroll
      for (int nt = 0; nt < 8; ++nt) {
        acc[nt] = __builtin_amdgcn_mfma_f32_16x16x32_bf16(
            afr[kt][0], df[nt], acc[nt], 0, 0, 0);
        acc[nt] = __builtin_amdgcn_mfma_f32_16x16x32_bf16(
            afr[kt][1], df[nt], acc[nt], 0, 0, 0);
      }
    }
    float rho_n = 1.f / (2.f * sigma1 - rho);
    float c1s = rho_n * rho;
    float c2s = 2.f * rho_n / delta;
#pragma unroll
    for (int nt = 0; nt < 8; ++nt) {
      ushort4 pack;
      unsigned short* pp = (unsigned short*)&pack;
#pragma unroll
      for (int rg = 0; rg < 4; ++rg) {
        xx[nt][rg] += dd[nt][rg];
        rr[nt][rg] -= acc[nt][rg];
        float dn = fmaf(c1s, dd[nt][rg], c2s * rr[nt][rg]);
        unsigned short dq = f2bf(dn);
        dd[nt][rg] = bf2f(dq);
        pp[rg] = dq;
      }
      *(ushort4*)(&dTw[nt * 2048 + wrA]) = pack;
    }
    rho = rho_n;
    __syncthreads();
  }

  // X -> hi/lo bf16 B-operand fragments, in place over B0 (same slot math).
  unsigned short* Xf = (unsigned short*)Bg;
#pragma unroll
  for (int nt = 0; nt < 8; ++nt) {
    ushort4 h4, l4;
    unsigned short* hp = (unsigned short*)&h4;
    unsigned short* lp = (unsigned short*)&l4;
#pragma unroll
    for (int rg = 0; rg < 4; ++rg) {
      float xv = xx[nt][rg];
      unsigned short h = f2bf(xv);
      hp[rg] = h;
      lp[rg] = f2bf(xv - bf2f(h));
    }
    size_t off = (size_t)nt * 2048 + wrA;
    *(ushort4*)(Xf + off) = h4;
    *(ushort4*)(Xf + 16384 + off) = l4;
  }
}

// ---------------------------------------------------------------------------
// Attention per (h,n), all-MFMA:
//   O = exp(cs)*(q@X) + tril(exp(cs_c-cs_j)*beta_j * q@k^T) @ v + alpha*v.
// ---------------------------------------------------------------------------
__global__ __launch_bounds__(256) void attn_kernel(
    const unsigned short* __restrict__ q16, const unsigned short* __restrict__ k16,
    const unsigned short* __restrict__ vT16, const unsigned short* __restrict__ Xf,
    const float* __restrict__ vs, const float* __restrict__ cs,
    const float* __restrict__ beta, const float* __restrict__ alpha,
    float* __restrict__ o) {
  int bid = blockIdx.x;             // h*16+n
  int h = bid >> 4, n = bid & 15;
  int hk = h >> 1;
  __shared__ unsigned short qb[64 * 136];   // rows are 128 bf16 + 8 pad
  __shared__ unsigned short kb[64 * 136];
  __shared__ unsigned short Sb[64 * 72];
  __shared__ float csL[64], ecsL[64], betaL[64], alphaL[64];
  int tid = threadIdx.x;
  int w = tid >> 6, lane = tid & 63;
  int ln = lane & 15, hi = lane >> 4;

  {
    size_t qgb = (((size_t)(n * 64)) * 16 + h) * 128;
    size_t kgb = (((size_t)(n * 64)) * 8 + hk) * 128;
#pragma unroll
    for (int g = 0; g < 4; ++g) {
      int i = tid + g * 256;
      int c = i >> 4, ch = i & 15;
      *(uint4*)(qb + c * 136 + ch * 8) =
          *(const uint4*)(q16 + qgb + (size_t)c * 2048 + ch * 8);
      *(uint4*)(kb + c * 136 + ch * 8) =
          *(const uint4*)(k16 + kgb + (size_t)c * 1024 + ch * 8);
    }
    if (tid < 64) {
      float cv = cs[bid * 64 + tid];
      csL[tid] = cv;
      ecsL[tid] = expf(cv);
      betaL[tid] = beta[(n * 64 + tid) * 16 + h];
      alphaL[tid] = alpha[(n * 64 + tid) * 16 + h];
    }
  }
  __syncthreads();

  short8 aq[4];
#pragma unroll
  for (int dt = 0; dt < 4; ++dt)
    aq[dt] = *(const short8*)(qb + (w * 16 + ln) * 136 + dt * 32 + hi * 8);

  // phase 1: o_inter = q @ X (hi+lo planes), then scale rows by exp(cs)
  const unsigned short* Xb = Xf + ((size_t)bid << 15);
  floatx4 acc[8];
#pragma unroll
  for (int et = 0; et < 8; ++et) {
    floatx4 a = (floatx4)(0.f);
#pragma unroll
    for (int dt = 0; dt < 4; ++dt) {
      short8 xh = *(const short8*)(Xb + (et * 4 + dt) * 512 + lane * 8);
      short8 xl = *(const short8*)(Xb + 16384 + (et * 4 + dt) * 512 + lane * 8);
      a = __builtin_amdgcn_mfma_f32_16x16x32_bf16(aq[dt], xh, a, 0, 0, 0);
      a = __builtin_amdgcn_mfma_f32_16x16x32_bf16(aq[dt], xl, a, 0, 0, 0);
    }
    acc[et] = a;
  }
#pragma unroll
  for (int et = 0; et < 8; ++et)
#pragma unroll
    for (int rg = 0; rg < 4; ++rg)
      acc[et][rg] *= ecsL[w * 16 + hi * 4 + rg];

  // phase 2: gated causal scores -> Sb (bf16), wave-local rows
#pragma unroll
  for (int jt = 0; jt < 4; ++jt) {
    if (jt <= w) {
      floatx4 s = (floatx4)(0.f);
#pragma unroll
      for (int dt = 0; dt < 4; ++dt) {
        short8 bk = *(const short8*)(kb + (jt * 16 + ln) * 136 + dt * 32 + hi * 8);
        s = __builtin_amdgcn_mfma_f32_16x16x32_bf16(aq[dt], bk, s, 0, 0, 0);
      }
      int j = jt * 16 + ln;
      float csj = csL[j], bj = betaL[j];
#pragma unroll
      for (int rg = 0; rg < 4; ++rg) {
        int c = w * 16 + hi * 4 + rg;
        float v = (j <= c) ? s[rg] * expf(csL[c] - csj) * bj : 0.f;
        Sb[c * 72 + j] = f2bf(v);
      }
    } else {
#pragma unroll
      for (int rg = 0; rg < 4; ++rg)
        Sb[(w * 16 + hi * 4 + rg) * 72 + jt * 16 + ln] = 0;
    }
  }

  // phase 3: O += S @ v
  const unsigned short* vTb = vT16 + ((size_t)(n * 8 + hk) << 13);
#pragma unroll
  for (int et = 0; et < 8; ++et) {
#pragma unroll
    for (int kt = 0; kt < 2; ++kt) {
      short8 as = *(const short8*)(Sb + (w * 16 + ln) * 72 + kt * 32 + hi * 8);
      short8 bv = *(const short8*)(vTb + (et * 16 + ln) * 64 + kt * 32 + hi * 8);
      acc[et] = __builtin_amdgcn_mfma_f32_16x16x32_bf16(as, bv, acc[et], 0, 0, 0);
    }
  }

  // epilogue: + alpha*v, store
#pragma unroll
  for (int et = 0; et < 8; ++et) {
#pragma unroll
    for (int rg = 0; rg < 4; ++rg) {
      int c = w * 16 + hi * 4 + rg, e = et * 16 + ln;
      size_t oaddr = (((size_t)(n * 64 + c)) * 16 + h) * 128 + e;
      size_t vaddr = (((size_t)(n * 64 + c)) * 8 + hk) * 128 + e;
      o[oaddr] = acc[et][rg] + alphaL[c] * vs[vaddr];
    }
  }
}

// ---------------------------------------------------------------------------
// rmso: gated RMSNorm -> bf16 (blocks 0..4095) + tcast(Wo) (4096..8191).
// ---------------------------------------------------------------------------
__global__ __launch_bounds__(256) void rmso_kernel(
    const float* __restrict__ o, const float* __restrict__ xall,
    const float* __restrict__ norm_w, unsigned short* __restrict__ onorm,
    const float* __restrict__ Wo, unsigned short* __restrict__ WtWo) {
  __shared__ float t[32 * 33];
  int b = blockIdx.x, tid = threadIdx.x;
  if (b < 4096) {
    int wave = tid >> 6, lane = tid & 63;
    int row = b * 4 + wave;          // t*16 + h
    size_t base = (size_t)row * HDIM;
    size_t gbase = (size_t)(row >> 4) * 6144 + 4096 + (size_t)(row & 15) * HDIM;
    float v0 = o[base + lane], v1 = o[base + lane + 64];
    float ss = fmaf(v0, v0, v1 * v1);
#pragma unroll
    for (int off = 32; off; off >>= 1) ss += __shfl_down(ss, off);
    ss = __shfl(ss, 0);
    float rinv = rsqrtf(ss * (1.f / 128.f) + 1e-6f);
    float g0 = xall[gbase + lane], g1 = xall[gbase + lane + 64];
    float s0 = g0 / (1.f + expf(-g0));
    float s1 = g1 / (1.f + expf(-g1));
    onorm[base + lane]      = f2bf(v0 * rinv * norm_w[lane] * s0);
    onorm[base + lane + 64] = f2bf(v1 * rinv * norm_w[lane + 64] * s1);
  } else {
    int r = b - 4096;
    tcast_body(Wo, WtWo, 2048, 2048, r & 63, r >> 6, tid, t);
  }
}

// ---------------------------------------------------------------------------
extern "C" void kernel_launch(void* const* d_in, const int* in_sizes, int n_in,
                              void* d_out, int out_size, void* d_ws,
                              size_t ws_size, hipStream_t stream) {
  (void)in_sizes; (void)n_in; (void)out_size; (void)ws_size;
  const float* x      = (const float*)d_in[0];
  const float* Wq     = (const float*)d_in[1];
  const float* Wk     = (const float*)d_in[2];
  const float* Wv     = (const float*)d_in[3];
  const float* convq  = (const float*)d_in[4];
  const float* convk  = (const float*)d_in[5];
  const float* convv  = (const float*)d_in[6];
  const float* Wa     = (const float*)d_in[7];
  const float* A_log  = (const float*)d_in[8];
  const float* dtb    = (const float*)d_in[9];
  const float* Wb     = (const float*)d_in[10];
  const float* bbv    = (const float*)d_in[11];
  const float* Wal    = (const float*)d_in[12];
  const float* balv   = (const float*)d_in[13];
  const float* Wg     = (const float*)d_in[14];
  const float* norm_w = (const float*)d_in[15];
  const float* Wo     = (const float*)d_in[16];
  float* out = (float*)d_out;

  // workspace layout (float slots), ~88.5 MB total
  float* p = (float*)d_ws;
  float* xall  = p; p += 6291456;   // [L][6144]: q|k|v|g projections
  float* qslot = p; p += 2097152;   // carved: qs16 | ks16 | vT16 (bf16)
  float* ks2   = p; p += 1048576;   // + vs2: reused as WtWo (bf16) post-attn
  float* vs2   = p; p += 1048576;
  float* ob    = p; p += 2097152;
  float* glog  = p; p += 16384;
  float* beta  = p; p += 16384;
  float* alpha = p; p += 16384;
  float* csb   = p; p += 16384;
  float* wend  = p; p += 16384;
  float* traces= p; p += 16384;     // 256 used
  float* dHn   = p; p += 4194304;   // -> A -> A-frags (bf16 hi/lo) in place
  float* dBn   = p; p += 4194304;   // -> B0 -> X-frags (bf16 hi/lo) in place
  unsigned short* xb16 = (unsigned short*)p; p += 1048576;

  unsigned short* qs16 = (unsigned short*)qslot;     // 1024*2048
  unsigned short* ks16 = qs16 + 2097152;             // 1024*1024
  unsigned short* vT16 = ks16 + 1048576;             // 128*128*64
  unsigned short* WtAll = (unsigned short*)dHn;      // 24 MB over dHn+dBn
  unsigned short* WtWo  = (unsigned short*)ks2;      // 8 MB over ks2+vs2
  unsigned short* onorm16 = xb16;                    // free after projections

  dim3 blk(256);
  // weight prep: castbf(x) + tcast q|k|v|g (WtAll rows 0|2048|3072|4096)
  prep_kernel<<<14336, blk, 0, stream>>>(x, Wq, Wk, Wv, Wg, xb16, WtAll);
  gemm_bf16<<<dim3(96, 8), blk, 0, stream>>>(xb16, WtAll, xall, 1024, 6144, 2048);
  // causal conv + silu (q scaled by HD^-0.5)
  conv_all<<<16384, blk, 0, stream>>>(xall, convq, convk, convv,
                                      qs16, ks2, ks16, vs2);
  vtr_kernel<<<128, blk, 0, stream>>>(vs2, vT16);
  // gates + cumulative decay
  gates_fused<<<1024, blk, 0, stream>>>(x, Wa, Wb, Wal, A_log, dtb, bbv, balv,
                                        glog, beta, alpha);
  cumsum_kernel<<<1, blk, 0, stream>>>(glog, beta, csb, wend);
  // gram increments (MFMA), scan, A-frag prep, Chebyshev
  dhb_kernel<<<256, blk, 0, stream>>>(ks2, vs2, wend, dHn, dBn);
  scan_kernel<<<1024, blk, 0, stream>>>(dHn, dBn, csb);
  afrag_kernel<<<256, blk, 0, stream>>>(dHn, traces);
  cheb_kernel<<<256, dim3(512), 0, stream>>>((unsigned short*)dHn, traces, dBn);
  // attention (all-MFMA)
  attn_kernel<<<256, blk, 0, stream>>>(qs16, ks16, vT16, (unsigned short*)dBn,
                                       vs2, csb, beta, alpha, ob);
  // gated RMSNorm (bf16 out) + tcast(Wo), then output projection
  rmso_kernel<<<8192, blk, 0, stream>>>(ob, xall, norm_w, onorm16, Wo, WtWo);
  gemm_bf16<<<dim3(32, 8), blk, 0, stream>>>(onorm16, WtWo, out, 1024, 2048, 2048);
}